// Round 15
// baseline (265.939 us; speedup 1.0000x reference)
//
#include <hip/hip_runtime.h>
#include <math.h>

// ---------------- problem constants ----------------
constexpr int Bn  = 128;
constexpr int Kd  = 65536;    // magnitude dim (phase half of feats is zeros)
constexpr int F1  = 128;
constexpr int F2  = 64;
constexpr int NM  = 3;
constexpr int Qd  = 256;
constexpr int NCH = 512;      // split-K chunks for big GEMM
constexpr int KC  = 128;      // k per chunk
constexpr int MSZ = 256 * 256;
constexpr int XSZ = 256 * 128;  // u32 slots per packed matrix

// Muon (growth) quintic Newton-Schulz coefficients
#define MA 3.4445f
#define MB (-4.7750f)
#define MC 2.0315f
// degree-9 convergent NS: x*(315 - 420y + 378y^2 - 180y^3 + 35y^4)/128, y=x^2
#define D9_0 (315.f / 128.f)
#define D9_1 (-420.f / 128.f)
#define D9_2 (378.f / 128.f)
#define D9_3 (-180.f / 128.f)
#define D9_4 (35.f / 128.f)

// ---------------- ws layout (float offsets) ----------------
constexpr size_t OFF_H1P = 0;                                    // 8,388,608
constexpr size_t OFF_H1  = OFF_H1P + (size_t)NCH * Bn * F1;
constexpr size_t OFF_SEL = OFF_H1 + (size_t)Bn * F1;
constexpr size_t OFF_PT  = OFF_SEL + 256;                        // NM*MSZ f32 (P^T)
constexpr size_t OFF_XPA = OFF_PT + (size_t)NM * MSZ;            // NM*XSZ u32
constexpr size_t OFF_XPB = OFF_XPA + (size_t)NM * XSZ;

// ---------------- f16 helpers ----------------
typedef __fp16 half2_t __attribute__((ext_vector_type(2)));
union HU { half2_t h; unsigned int u; };
__device__ __forceinline__ unsigned int pkh(float x, float y) {
  HU v; v.h = __builtin_amdgcn_cvt_pkrtz(x, y); return v.u;
}
__device__ __forceinline__ half2_t uh(unsigned int u) { HU v; v.u = u; return v.h; }

#if __has_builtin(__builtin_amdgcn_fdot2)
#define FDOT2(a, b, c) __builtin_amdgcn_fdot2((a), (b), (c), false)
#else
#define FDOT2(a, b, c) ((c) + (float)(a)[0] * (float)(b)[0] + (float)(a)[1] * (float)(b)[1])
#endif

// ---------------- bf16 helpers (MFMA GEMM) ----------------
typedef short bf16x8 __attribute__((ext_vector_type(8)));
typedef float f32x4 __attribute__((ext_vector_type(4)));
__device__ __forceinline__ unsigned short bh(float x) {   // RNE fp32 -> bf16
  unsigned int bx = __float_as_uint(x);
  return (unsigned short)((bx + 0x7FFFu + ((bx >> 16) & 1u)) >> 16);
}
__device__ __forceinline__ float bf(unsigned short h) {
  return __uint_as_float((unsigned int)h << 16);
}

// ---------------- K1: split-K magnitude GEMM via bf16-split MFMA (R10, proven) ----------------
__global__ __launch_bounds__(256) void k_gemm1(const float* __restrict__ sp,
                                               const float* __restrict__ W1,
                                               float* __restrict__ h1p) {
  __shared__ short Ah[128][72];
  __shared__ short Al[128][72];
  __shared__ short Bh[128][72];
  __shared__ short Bl[128][72];
  const int t = threadIdx.x;
  const int w = t >> 6, l = t & 63;
  const int l15 = l & 15, lg = l >> 4;
  const int ch = blockIdx.x;
  const size_t k0 = (size_t)ch * KC;
  const int srow = t >> 4;
  const int skq  = (t & 15) * 4;

  f32x4 acc[2][8];
#pragma unroll
  for (int r = 0; r < 2; ++r)
#pragma unroll
    for (int c = 0; c < 8; ++c) acc[r][c] = (f32x4){0.f, 0.f, 0.f, 0.f};

#pragma unroll
  for (int sub = 0; sub < 2; ++sub) {
    __syncthreads();
    const size_t kb = k0 + sub * 64 + skq;
#pragma unroll
    for (int rep = 0; rep < 8; ++rep) {
      const int row = srow + rep * 16;
      const float4 av = *(const float4*)(sp + (size_t)row * Kd + kb);
      const float4 bv = *(const float4*)(W1 + (size_t)row * (2 * Kd) + kb);
      float va[4] = {fabsf(av.x), fabsf(av.y), fabsf(av.z), fabsf(av.w)};
      float vb[4] = {bv.x, bv.y, bv.z, bv.w};
      unsigned short ha[4], la[4], hb[4], lb[4];
#pragma unroll
      for (int e = 0; e < 4; ++e) {
        ha[e] = bh(va[e]); la[e] = bh(va[e] - bf(ha[e]));
        hb[e] = bh(vb[e]); lb[e] = bh(vb[e] - bf(hb[e]));
      }
      *(uint2*)&Ah[row][skq] = make_uint2((unsigned)ha[0] | ((unsigned)ha[1] << 16),
                                          (unsigned)ha[2] | ((unsigned)ha[3] << 16));
      *(uint2*)&Al[row][skq] = make_uint2((unsigned)la[0] | ((unsigned)la[1] << 16),
                                          (unsigned)la[2] | ((unsigned)la[3] << 16));
      *(uint2*)&Bh[row][skq] = make_uint2((unsigned)hb[0] | ((unsigned)hb[1] << 16),
                                          (unsigned)hb[2] | ((unsigned)hb[3] << 16));
      *(uint2*)&Bl[row][skq] = make_uint2((unsigned)lb[0] | ((unsigned)lb[1] << 16),
                                          (unsigned)lb[2] | ((unsigned)lb[3] << 16));
    }
    __syncthreads();
#pragma unroll
    for (int ks = 0; ks < 2; ++ks) {
      const int ko = ks * 32 + lg * 8;
      bf16x8 afh[2], afl[2];
#pragma unroll
      for (int r = 0; r < 2; ++r) {
        const int row = w * 32 + r * 16 + l15;
        afh[r] = *(const bf16x8*)&Ah[row][ko];
        afl[r] = *(const bf16x8*)&Al[row][ko];
      }
#pragma unroll
      for (int c = 0; c < 8; ++c) {
        const int col = c * 16 + l15;
        const bf16x8 bfh = *(const bf16x8*)&Bh[col][ko];
        const bf16x8 bfl = *(const bf16x8*)&Bl[col][ko];
#pragma unroll
        for (int r = 0; r < 2; ++r) {
          acc[r][c] = __builtin_amdgcn_mfma_f32_16x16x32_bf16(afh[r], bfh, acc[r][c], 0, 0, 0);
          acc[r][c] = __builtin_amdgcn_mfma_f32_16x16x32_bf16(afh[r], bfl, acc[r][c], 0, 0, 0);
          acc[r][c] = __builtin_amdgcn_mfma_f32_16x16x32_bf16(afl[r], bfh, acc[r][c], 0, 0, 0);
        }
      }
    }
  }

  float* outp = h1p + (size_t)ch * (Bn * F1);
#pragma unroll
  for (int r = 0; r < 2; ++r)
#pragma unroll
    for (int c = 0; c < 8; ++c) {
      const int col = c * 16 + l15;
#pragma unroll
      for (int reg = 0; reg < 4; ++reg) {
        const int row = w * 32 + r * 16 + lg * 4 + reg;
        outp[row * F1 + col] = acc[r][c][reg];
      }
    }
}

// ---------------- K1b: reduce partials + bias + relu (512 chunks) ----------------
__global__ __launch_bounds__(256) void k_red(const float* __restrict__ h1p,
                                             const float* __restrict__ b1,
                                             float* __restrict__ h1) {
  const int t = threadIdx.x;
  const int ol = t & 63;
  const int g = t >> 6;
  const int o = blockIdx.x * 64 + ol;
  double s = 0.0;
#pragma unroll 8
  for (int c = g * 128; c < g * 128 + 128; ++c)
    s += (double)h1p[(size_t)c * (Bn * F1) + o];
  __shared__ double red[4][64];
  red[g][ol] = s;
  __syncthreads();
  if (g == 0) {
    const double v = red[0][ol] + red[1][ol] + red[2][ol] + red[3][ol];
    const float r = (float)v + b1[o & 127];
    h1[o] = fmaxf(r, 0.f);
  }
}

// ---------------- K2: small MLP + syndrome + selection ----------------
__global__ __launch_bounds__(256) void k_mlp(const float* __restrict__ h1,
                                             const float* __restrict__ W2,
                                             const float* __restrict__ b2,
                                             const float* __restrict__ W3,
                                             const float* __restrict__ b3,
                                             int* __restrict__ sel) {
  const int t = threadIdx.x;
  const int b0 = blockIdx.x * 16;
  __shared__ float h2s[16 * 64];
  for (int o = t; o < 16 * 64; o += 256) {
    const int bl = o >> 6, j = o & 63;
    const float* hr = h1 + (b0 + bl) * F1;
    const float* wr = W2 + j * F1;
    float s = b2[j];
    for (int k = 0; k < F1; ++k) s += hr[k] * wr[k];
    h2s[o] = fmaxf(s, 0.f);
  }
  __syncthreads();
  if (t < 16) {
    const int b = b0 + t;
    float best = -1.f;
    int bi = 0;
    bool needed = false;
    for (int j = 0; j < 8; ++j) {
      double s = (double)b3[j];
      const float* wr = W3 + j * F2;
      for (int k = 0; k < F2; ++k) s += (double)h2s[t * F2 + k] * (double)wr[k];
      const float a = fabsf((float)s);
      if (a > 1e-4f) needed = true;
      if (a > best) { best = a; bi = j; }
    }
    sel[b] = needed ? (bi % NM) : -1;
  }
}

// ---------------- LDS pass helpers ----------------
// col-pass: W = X^T V for 4 RHS; thread = (col c = t>>1, half hh = t&1).
// All lanes read the same row r per iter: XL[r][cp] = 16 distinct words
// (4-lane broadcast each) on 16 distinct banks; V strips [4][260] are
// stride-1-word -> per-j read is a 2-address (hh split) broadcast = free.
__device__ __forceinline__ void col_pass(const unsigned int (*__restrict__ XL)[131],
                                         const float (*__restrict__ V)[260],
                                         uint4* __restrict__ pkT,
                                         const int t) {
  const int c = t >> 1, hh = t & 1, sel = c & 1, cp = c >> 1;
  float a0 = 0, a1 = 0, a2 = 0, a3 = 0;
  const int rb = hh * 128;
#pragma unroll 8
  for (int i = 0; i < 128; ++i) {
    const int r = rb + i;
    const half2_t xh = uh(XL[r][cp]);
    const float x = (float)xh[sel];
    a0 += x * V[0][r]; a1 += x * V[1][r]; a2 += x * V[2][r]; a3 += x * V[3][r];
  }
  // combine the two row-halves (lanes 2c, 2c+1)
  a0 += __shfl_down(a0, 1, 2);
  a1 += __shfl_down(a1, 1, 2);
  a2 += __shfl_down(a2, 1, 2);
  a3 += __shfl_down(a3, 1, 2);
  // lane 4k holds W[2k][:], lane 4k+2 holds W[2k+1][:] -> pair and pack
  const float b0 = __shfl_down(a0, 2, 4);
  const float b1 = __shfl_down(a1, 2, 4);
  const float b2 = __shfl_down(a2, 2, 4);
  const float b3 = __shfl_down(a3, 2, 4);
  if ((t & 3) == 0)
    pkT[c >> 1] = make_uint4(pkh(a0, b0), pkh(a1, b1), pkh(a2, b2), pkh(a3, b3));
}

// row-pass: U = X W for 4 RHS; thread = (row q = t>>1, half hh = t&1)
// after the shfl, even lanes (hh==0) hold the full dot for row q.
__device__ __forceinline__ void row_pass(const unsigned int (*__restrict__ XL)[131],
                                         const uint4* __restrict__ pkT,
                                         const int t, float b[4]) {
  const int q = t >> 1, hh = t & 1;
  float b0 = 0, b1 = 0, b2 = 0, b3 = 0;
  const int kb = hh * 64;
#pragma unroll 8
  for (int kk = 0; kk < 64; ++kk) {
    const half2_t xh = uh(XL[q][kb + kk]);
    const uint4 wv = pkT[kb + kk];
    b0 = FDOT2(xh, uh(wv.x), b0);
    b1 = FDOT2(xh, uh(wv.y), b1);
    b2 = FDOT2(xh, uh(wv.z), b2);
    b3 = FDOT2(xh, uh(wv.w), b3);
  }
  b0 += __shfl_down(b0, 1, 2);
  b1 += __shfl_down(b1, 1, 2);
  b2 += __shfl_down(b2, 1, 2);
  b3 += __shfl_down(b3, 1, 2);
  b[0] = b0; b[1] = b1; b[2] = b2; b[3] = b3;
}

// ---------------- NS Muon iteration: one dispatch, X LDS-resident ----------------
// block owns cols j0..j0+3: X' = ca*V0 + cb*X(X^T V0) + cc*X(X^T(X(X^T V0)))
// first=1: stage from ops f32, compute Frobenius scale block-locally.
__global__ __launch_bounds__(512) void k_it(const float* __restrict__ ops,
                                            const unsigned int* __restrict__ XP,
                                            unsigned int* __restrict__ XPn,
                                            const int first) {
  const int m = blockIdx.x >> 6, g = blockIdx.x & 63;
  unsigned int* xpn = XPn + (size_t)m * XSZ;
  const int t = threadIdx.x;

  __shared__ unsigned int XL[256][131];
  __shared__ float fV[4][260];
  __shared__ float fU[4][260];
  __shared__ uint4 pkT[132];
  __shared__ float rq[8];

  float ca = MA, cb = MB, cc = MC;
  if (first) {
    const float* Cm = ops + (size_t)m * MSZ;
    float ssq = 0.f;
#pragma unroll 8
    for (int i = 0; i < 64; ++i) {
      const int fl = i * 512 + t;               // f16-pair index
      const float2 v = *(const float2*)&Cm[2 * fl];
      ssq += v.x * v.x + v.y * v.y;
      XL[fl >> 7][fl & 127] = pkh(v.x, v.y);
    }
#pragma unroll
    for (int o = 32; o; o >>= 1) ssq += __shfl_down(ssq, o, 64);
    if ((t & 63) == 0) rq[t >> 6] = ssq;
    __syncthreads();
    float s2 = 0.f;
#pragma unroll
    for (int q2 = 0; q2 < 8; ++q2) s2 += rq[q2];
    const float s = 0.15f * sqrtf(s2);          // 1.2 * 2||C||_F / sqrt(256)
    const float is = 1.f / s, is2 = is * is;
    ca = MA * is; cb = MB * is * is2; cc = MC * is * is2 * is2;
  } else {
    const unsigned int* xp = XP + (size_t)m * XSZ;
#pragma unroll 8
    for (int i = 0; i < 64; ++i) {
      const int fl = i * 512 + t;
      XL[fl >> 7][fl & 127] = xp[fl];
    }
  }
  __syncthreads();

  // stage V0 = X[:, 4g..4g+3] into f32 strips
  if (t < 256) {
    const half2_t h0 = uh(XL[t][2 * g]), h1 = uh(XL[t][2 * g + 1]);
    fV[0][t] = (float)h0[0]; fV[1][t] = (float)h0[1];
    fV[2][t] = (float)h1[0]; fV[3][t] = (float)h1[1];
  }
  __syncthreads();

  col_pass(XL, fV, pkT, t);   // W1 = X^T V0
  __syncthreads();
  float b[4];
  row_pass(XL, pkT, t, b);    // U1 = X W1
  const int q = t >> 1, hh = t & 1;
  if (!hh) { fU[0][q] = b[0]; fU[1][q] = b[1]; fU[2][q] = b[2]; fU[3][q] = b[3]; }
  __syncthreads();

  col_pass(XL, fU, pkT, t);   // W2 = X^T U1
  __syncthreads();
  row_pass(XL, pkT, t, b);    // U2 = X W2
  if (!hh) {
    const float r0 = ca * fV[0][q] + cb * fU[0][q] + cc * b[0];
    const float r1 = ca * fV[1][q] + cb * fU[1][q] + cc * b[1];
    const float r2 = ca * fV[2][q] + cb * fU[2][q] + cc * b[2];
    const float r3 = ca * fV[3][q] + cb * fU[3][q] + cc * b[3];
    xpn[q * 128 + 2 * g]     = pkh(r0, r1);
    xpn[q * 128 + 2 * g + 1] = pkh(r2, r3);
  }
}

// ---------------- NS degree-9 convergent final: writes P^T fp32 ----------------
__global__ __launch_bounds__(512) void k_d9(const unsigned int* __restrict__ XP,
                                            float* __restrict__ PT) {
  const int m = blockIdx.x >> 6, g = blockIdx.x & 63;
  const unsigned int* xp = XP + (size_t)m * XSZ;
  float* ptm = PT + (size_t)m * MSZ;
  const int t = threadIdx.x;

  __shared__ unsigned int XL[256][131];
  __shared__ float fV[4][260];
  __shared__ uint4 pkT[132];

#pragma unroll 8
  for (int i = 0; i < 64; ++i) {
    const int fl = i * 512 + t;
    XL[fl >> 7][fl & 127] = xp[fl];
  }
  __syncthreads();
  if (t < 256) {
    const half2_t h0 = uh(XL[t][2 * g]), h1 = uh(XL[t][2 * g + 1]);
    fV[0][t] = (float)h0[0]; fV[1][t] = (float)h0[1];
    fV[2][t] = (float)h1[0]; fV[3][t] = (float)h1[1];
  }
  __syncthreads();

  const int q = t >> 1, hh = t & 1;
  float o0 = 0, o1 = 0, o2 = 0, o3 = 0;
  if (!hh) {
    o0 = D9_0 * fV[0][q]; o1 = D9_0 * fV[1][q];
    o2 = D9_0 * fV[2][q]; o3 = D9_0 * fV[3][q];
  }

  float b[4];
#pragma unroll
  for (int p = 1; p <= 4; ++p) {
    const float cp = (p == 1) ? D9_1 : (p == 2) ? D9_2 : (p == 3) ? D9_3 : D9_4;
    col_pass(XL, fV, pkT, t);
    __syncthreads();
    row_pass(XL, pkT, t, b);
    if (!hh) {
      o0 += cp * b[0]; o1 += cp * b[1]; o2 += cp * b[2]; o3 += cp * b[3];
      if (p < 4) { fV[0][q] = b[0]; fV[1][q] = b[1]; fV[2][q] = b[2]; fV[3][q] = b[3]; }
    }
    __syncthreads();
  }

  if (!hh) {
    ptm[(4 * g + 0) * 256 + q] = o0;
    ptm[(4 * g + 1) * 256 + q] = o1;
    ptm[(4 * g + 2) * 256 + q] = o2;
    ptm[(4 * g + 3) * 256 + q] = o3;
  }
}

// ---------------- K4: output assembly (reads P^T, coalesced) ----------------
__global__ __launch_bounds__(256) void k_out(const float* __restrict__ sp,
                                             const float* __restrict__ PT,
                                             const int* __restrict__ sel,
                                             float* __restrict__ out) {
  const int t = threadIdx.x;
  if (blockIdx.x < 128) {
    const int b = blockIdx.x;
    __shared__ float hd[256];
    hd[t] = sp[(size_t)b * Kd + t];
    __syncthreads();
    const int s = sel[b];
    if (s < 0) {
      out[(size_t)b * Kd + t] = hd[t];
    } else {
      const float* pt = PT + (size_t)s * MSZ;
      float acc = 0.f;
#pragma unroll 8
      for (int j = 0; j < 256; ++j) acc += pt[j * 256 + t] * hd[j];
      out[(size_t)b * Kd + t] = hd[t] + 0.1f * acc;
    }
  } else {
    const int ci = blockIdx.x - 128;
    const float4* in4 = (const float4*)sp;
    float4* out4 = (float4*)out;
    const int total = Bn * (Kd / 4);
    for (int i = ci * 256 + t; i < total; i += 2048 * 256) {
      const int pos = i & ((Kd / 4) - 1);
      if (pos >= Qd / 4) out4[i] = in4[i];
    }
  }
}

// ---------------- host ----------------
extern "C" void kernel_launch(void* const* d_in, const int* in_sizes, int n_in,
                              void* d_out, int out_size, void* d_ws, size_t ws_size,
                              hipStream_t stream) {
  (void)in_sizes; (void)n_in; (void)out_size; (void)ws_size;
  const float* sp = (const float*)d_in[0];
  const float* W1 = (const float*)d_in[1];
  const float* b1 = (const float*)d_in[2];
  const float* W2 = (const float*)d_in[3];
  const float* b2 = (const float*)d_in[4];
  const float* W3 = (const float*)d_in[5];
  const float* b3 = (const float*)d_in[6];
  const float* ops = (const float*)d_in[7];
  float* out = (float*)d_out;
  float* ws = (float*)d_ws;

  float* h1p  = ws + OFF_H1P;
  float* h1   = ws + OFF_H1;
  int*   sel  = (int*)(ws + OFF_SEL);
  float* PT   = ws + OFF_PT;
  unsigned int* XPa = (unsigned int*)(ws + OFF_XPA);
  unsigned int* XPb = (unsigned int*)(ws + OFF_XPB);

  k_gemm1<<<NCH, 256, 0, stream>>>(sp, W1, h1p);
  k_red<<<256, 256, 0, stream>>>(h1p, b1, h1);
  k_mlp<<<8, 256, 0, stream>>>(h1, W2, b2, W3, b3, sel);

  // 7 Muon iterations (first stages from ops + folds 1/s), then degree-9 convergent
  k_it<<<192, 512, 0, stream>>>(ops, XPa, XPb, 1);
  unsigned int *XPc = XPb, *XPn = XPa;
  for (int it = 1; it < 7; ++it) {
    k_it<<<192, 512, 0, stream>>>(ops, XPc, XPn, 0);
    unsigned int* tp = XPc; XPc = XPn; XPn = tp;
  }
  k_d9<<<192, 512, 0, stream>>>(XPc, PT);

  k_out<<<128 + 2048, 256, 0, stream>>>(sp, PT, sel, out);
}

// Round 16
// 190.889 us; speedup vs baseline: 1.3932x; 1.3932x over previous
//
#include <hip/hip_runtime.h>
#include <math.h>

// ---------------- problem constants ----------------
constexpr int Bn  = 128;
constexpr int Kd  = 65536;    // magnitude dim (phase half of feats is zeros)
constexpr int F1  = 128;
constexpr int F2  = 64;
constexpr int NM  = 3;
constexpr int Qd  = 256;
constexpr int NCH = 512;      // split-K chunks for big GEMM
constexpr int KC  = 128;      // k per chunk
constexpr int MSZ = 256 * 256;

// Muon (growth) quintic Newton-Schulz coefficients
#define MA 3.4445f
#define MB (-4.7750f)
#define MC 2.0315f
// degree-9 convergent NS: x*(315 - 420y + 378y^2 - 180y^3 + 35y^4)/128, y=x^2
#define D9_0 (315.f / 128.f)
#define D9_1 (-420.f / 128.f)
#define D9_2 (378.f / 128.f)
#define D9_3 (-180.f / 128.f)
#define D9_4 (35.f / 128.f)

// ---------------- ws layout (float offsets) ----------------
constexpr size_t OFF_H1P  = 0;                                   // 512*128*128 floats
constexpr size_t OFF_H1   = OFF_H1P + (size_t)NCH * Bn * F1;
constexpr size_t OFF_SEL  = OFF_H1 + (size_t)Bn * F1;
constexpr size_t OFF_PART = OFF_SEL + 128;
constexpr size_t OFF_XA   = OFF_PART + 64;
constexpr size_t OFF_XB   = OFF_XA + (size_t)NM * MSZ;
constexpr size_t OFF_ACP  = OFF_XB + (size_t)NM * MSZ;           // u32: NM*128*256

// ---------------- f16 helpers (NS chain) ----------------
typedef __fp16 half2_t __attribute__((ext_vector_type(2)));
union HU { half2_t h; unsigned int u; };
__device__ __forceinline__ unsigned int pkh(float x, float y) {
  HU v; v.h = __builtin_amdgcn_cvt_pkrtz(x, y); return v.u;
}
__device__ __forceinline__ half2_t uh(unsigned int u) { HU v; v.u = u; return v.h; }

#if __has_builtin(__builtin_amdgcn_fdot2)
#define FDOT2(a, b, c) __builtin_amdgcn_fdot2((a), (b), (c), false)
#else
#define FDOT2(a, b, c) ((c) + (float)(a)[0] * (float)(b)[0] + (float)(a)[1] * (float)(b)[1])
#endif

// ---------------- bf16 helpers (MFMA GEMM) ----------------
typedef short bf16x8 __attribute__((ext_vector_type(8)));
typedef float f32x4 __attribute__((ext_vector_type(4)));
__device__ __forceinline__ unsigned short bh(float x) {   // RNE fp32 -> bf16
  unsigned int bx = __float_as_uint(x);
  return (unsigned short)((bx + 0x7FFFu + ((bx >> 16) & 1u)) >> 16);
}
__device__ __forceinline__ float bf(unsigned short h) {
  return __uint_as_float((unsigned int)h << 16);
}

// ---------------- K1: split-K magnitude GEMM via bf16-split MFMA (R10, proven) ----------------
__global__ __launch_bounds__(256) void k_gemm1(const float* __restrict__ sp,
                                               const float* __restrict__ W1,
                                               float* __restrict__ h1p) {
  __shared__ short Ah[128][72];
  __shared__ short Al[128][72];
  __shared__ short Bh[128][72];
  __shared__ short Bl[128][72];
  const int t = threadIdx.x;
  const int w = t >> 6, l = t & 63;
  const int l15 = l & 15, lg = l >> 4;
  const int ch = blockIdx.x;
  const size_t k0 = (size_t)ch * KC;
  const int srow = t >> 4;
  const int skq  = (t & 15) * 4;

  f32x4 acc[2][8];
#pragma unroll
  for (int r = 0; r < 2; ++r)
#pragma unroll
    for (int c = 0; c < 8; ++c) acc[r][c] = (f32x4){0.f, 0.f, 0.f, 0.f};

#pragma unroll
  for (int sub = 0; sub < 2; ++sub) {
    __syncthreads();
    const size_t kb = k0 + sub * 64 + skq;
#pragma unroll
    for (int rep = 0; rep < 8; ++rep) {
      const int row = srow + rep * 16;
      const float4 av = *(const float4*)(sp + (size_t)row * Kd + kb);
      const float4 bv = *(const float4*)(W1 + (size_t)row * (2 * Kd) + kb);
      float va[4] = {fabsf(av.x), fabsf(av.y), fabsf(av.z), fabsf(av.w)};
      float vb[4] = {bv.x, bv.y, bv.z, bv.w};
      unsigned short ha[4], la[4], hb[4], lb[4];
#pragma unroll
      for (int e = 0; e < 4; ++e) {
        ha[e] = bh(va[e]); la[e] = bh(va[e] - bf(ha[e]));
        hb[e] = bh(vb[e]); lb[e] = bh(vb[e] - bf(hb[e]));
      }
      *(uint2*)&Ah[row][skq] = make_uint2((unsigned)ha[0] | ((unsigned)ha[1] << 16),
                                          (unsigned)ha[2] | ((unsigned)ha[3] << 16));
      *(uint2*)&Al[row][skq] = make_uint2((unsigned)la[0] | ((unsigned)la[1] << 16),
                                          (unsigned)la[2] | ((unsigned)la[3] << 16));
      *(uint2*)&Bh[row][skq] = make_uint2((unsigned)hb[0] | ((unsigned)hb[1] << 16),
                                          (unsigned)hb[2] | ((unsigned)hb[3] << 16));
      *(uint2*)&Bl[row][skq] = make_uint2((unsigned)lb[0] | ((unsigned)lb[1] << 16),
                                          (unsigned)lb[2] | ((unsigned)lb[3] << 16));
    }
    __syncthreads();
#pragma unroll
    for (int ks = 0; ks < 2; ++ks) {
      const int ko = ks * 32 + lg * 8;
      bf16x8 afh[2], afl[2];
#pragma unroll
      for (int r = 0; r < 2; ++r) {
        const int row = w * 32 + r * 16 + l15;
        afh[r] = *(const bf16x8*)&Ah[row][ko];
        afl[r] = *(const bf16x8*)&Al[row][ko];
      }
#pragma unroll
      for (int c = 0; c < 8; ++c) {
        const int col = c * 16 + l15;
        const bf16x8 bfh = *(const bf16x8*)&Bh[col][ko];
        const bf16x8 bfl = *(const bf16x8*)&Bl[col][ko];
#pragma unroll
        for (int r = 0; r < 2; ++r) {
          acc[r][c] = __builtin_amdgcn_mfma_f32_16x16x32_bf16(afh[r], bfh, acc[r][c], 0, 0, 0);
          acc[r][c] = __builtin_amdgcn_mfma_f32_16x16x32_bf16(afh[r], bfl, acc[r][c], 0, 0, 0);
          acc[r][c] = __builtin_amdgcn_mfma_f32_16x16x32_bf16(afl[r], bfh, acc[r][c], 0, 0, 0);
        }
      }
    }
  }

  float* outp = h1p + (size_t)ch * (Bn * F1);
#pragma unroll
  for (int r = 0; r < 2; ++r)
#pragma unroll
    for (int c = 0; c < 8; ++c) {
      const int col = c * 16 + l15;
#pragma unroll
      for (int reg = 0; reg < 4; ++reg) {
        const int row = w * 32 + r * 16 + lg * 4 + reg;
        outp[row * F1 + col] = acc[r][c][reg];
      }
    }
}

// ---------------- K1b: reduce partials + bias + relu (512 chunks) ----------------
__global__ __launch_bounds__(256) void k_red(const float* __restrict__ h1p,
                                             const float* __restrict__ b1,
                                             float* __restrict__ h1) {
  const int t = threadIdx.x;
  const int ol = t & 63;
  const int g = t >> 6;
  const int o = blockIdx.x * 64 + ol;
  double s = 0.0;
#pragma unroll 8
  for (int c = g * 128; c < g * 128 + 128; ++c)
    s += (double)h1p[(size_t)c * (Bn * F1) + o];
  __shared__ double red[4][64];
  red[g][ol] = s;
  __syncthreads();
  if (g == 0) {
    const double v = red[0][ol] + red[1][ol] + red[2][ol] + red[3][ol];
    const float r = (float)v + b1[o & 127];
    h1[o] = fmaxf(r, 0.f);
  }
}

// ---------------- K2: small MLP + syndrome + selection ----------------
__global__ __launch_bounds__(256) void k_mlp(const float* __restrict__ h1,
                                             const float* __restrict__ W2,
                                             const float* __restrict__ b2,
                                             const float* __restrict__ W3,
                                             const float* __restrict__ b3,
                                             int* __restrict__ sel) {
  const int t = threadIdx.x;
  const int b0 = blockIdx.x * 16;
  __shared__ float h2s[16 * 64];
  for (int o = t; o < 16 * 64; o += 256) {
    const int bl = o >> 6, j = o & 63;
    const float* hr = h1 + (b0 + bl) * F1;
    const float* wr = W2 + j * F1;
    float s = b2[j];
    for (int k = 0; k < F1; ++k) s += hr[k] * wr[k];
    h2s[o] = fmaxf(s, 0.f);
  }
  __syncthreads();
  if (t < 16) {
    const int b = b0 + t;
    float best = -1.f;
    int bi = 0;
    bool needed = false;
    for (int j = 0; j < 8; ++j) {
      double s = (double)b3[j];
      const float* wr = W3 + j * F2;
      for (int k = 0; k < F2; ++k) s += (double)h2s[t * F2 + k] * (double)wr[k];
      const float a = fabsf((float)s);
      if (a > 1e-4f) needed = true;
      if (a > best) { best = a; bi = j; }
    }
    sel[b] = needed ? (bi % NM) : -1;
  }
}

// ---------------- NS phase A: A = X^T X -> f16 colpk (symmetric 32x32 tiles) ----------------
__global__ __launch_bounds__(512) void k_pA(const float* __restrict__ Xs,
                                            unsigned int* __restrict__ Acp,
                                            float* __restrict__ part) {
  const int bid = blockIdx.x;
  const int m = bid / 36;
  int rem = bid % 36;
  int I = 0;
  while (rem >= 8 - I) { rem -= 8 - I; ++I; }
  const int J = I + rem;
  const float* Xm = Xs + (size_t)m * MSZ;
  unsigned int* Am = Acp + (size_t)m * (128 * 256);
  __shared__ float PI[32][260];
  __shared__ float PJb[32][260];
  __shared__ float red[7][64][17];
  __shared__ float tr8[8];
  float (*PJ)[260] = (I == J) ? PI : PJb;
  const int t = threadIdx.x;

#pragma unroll
  for (int it = 0; it < 4; ++it) {
    const int task = it * 512 + t;
    const int k = task >> 3, c4 = task & 7;
    const float4 vI = *(const float4*)&Xm[k * 256 + I * 32 + c4 * 4];
#pragma unroll
    for (int e = 0; e < 4; ++e) PI[c4 * 4 + e][k] = (&vI.x)[e];
    if (I != J) {
      const float4 vJ = *(const float4*)&Xm[k * 256 + J * 32 + c4 * 4];
#pragma unroll
      for (int e = 0; e < 4; ++e) PJb[c4 * 4 + e][k] = (&vJ.x)[e];
    }
  }
  __syncthreads();

  const int h = t >> 6, u = t & 63, ur = u >> 3, uc = u & 7;
  float a[4][4];
#pragma unroll
  for (int i = 0; i < 4; ++i)
#pragma unroll
    for (int j = 0; j < 4; ++j) a[i][j] = 0.f;

  const int kb = h * 32;
#pragma unroll 8
  for (int kk = 0; kk < 32; ++kk) {
    const int k = kb + kk;
    float xi[4], xj[4];
#pragma unroll
    for (int i = 0; i < 4; ++i) xi[i] = PI[ur * 4 + i][k];
#pragma unroll
    for (int j = 0; j < 4; ++j) xj[j] = PJ[uc * 4 + j][k];
#pragma unroll
    for (int i = 0; i < 4; ++i)
#pragma unroll
      for (int j = 0; j < 4; ++j) a[i][j] += xi[i] * xj[j];
  }
  if (h) {
    float* rr = &red[h - 1][u][0];
#pragma unroll
    for (int i = 0; i < 4; ++i)
#pragma unroll
      for (int j = 0; j < 4; ++j) rr[i * 4 + j] = a[i][j];
  }
  __syncthreads();
  if (h == 0) {
#pragma unroll
    for (int i = 0; i < 4; ++i)
#pragma unroll
      for (int j = 0; j < 4; ++j) {
        float s = a[i][j];
#pragma unroll
        for (int q = 0; q < 7; ++q) s += red[q][u][i * 4 + j];
        a[i][j] = s;
      }
    const int gr = I * 32 + ur * 4, gc = J * 32 + uc * 4;
    {
      const int kp = gr >> 1;
      *(uint4*)&Am[kp * 256 + gc] =
          make_uint4(pkh(a[0][0], a[1][0]), pkh(a[0][1], a[1][1]),
                     pkh(a[0][2], a[1][2]), pkh(a[0][3], a[1][3]));
      *(uint4*)&Am[(kp + 1) * 256 + gc] =
          make_uint4(pkh(a[2][0], a[3][0]), pkh(a[2][1], a[3][1]),
                     pkh(a[2][2], a[3][2]), pkh(a[2][3], a[3][3]));
    }
    if (I != J) {
      const int kp = gc >> 1;
      *(uint4*)&Am[kp * 256 + gr] =
          make_uint4(pkh(a[0][0], a[0][1]), pkh(a[1][0], a[1][1]),
                     pkh(a[2][0], a[2][1]), pkh(a[3][0], a[3][1]));
      *(uint4*)&Am[(kp + 1) * 256 + gr] =
          make_uint4(pkh(a[0][2], a[0][3]), pkh(a[1][2], a[1][3]),
                     pkh(a[2][2], a[2][3]), pkh(a[3][2], a[3][3]));
    } else if (ur == uc) {
      tr8[ur] = a[0][0] + a[1][1] + a[2][2] + a[3][3];
    }
  }
  if (I == J) {
    __syncthreads();
    if (t == 0) {
      float s = 0.f;
#pragma unroll
      for (int q = 0; q < 8; ++q) s += tr8[q];
      part[m * 8 + I] = s;
    }
  }
}

// ---------------- NS phase B (Muon quintic), 2-row strips (grid NM*128) ----------------
// X' = ca*X + cb*(XA) + cc*(XAA); same k-split and summation order as R10 (bitwise-equal).
__global__ __launch_bounds__(512) void k_pB(const float* __restrict__ Xs,
                                            const unsigned int* __restrict__ Acp,
                                            const float* __restrict__ part,
                                            float* __restrict__ Xn,
                                            const float qa, const float qb, const float qc,
                                            const int first) {
  const int m = blockIdx.x >> 7, g = blockIdx.x & 127, i0 = g * 2;
  const float* Xm = Xs + (size_t)m * MSZ;
  const uint4* A4 = (const uint4*)(Acp + (size_t)m * (128 * 256));
  float* Xo = Xn + (size_t)m * MSZ;
  const int t = threadIdx.x, h = t >> 6, u = t & 63;
  __shared__ float xs[2][260];
  __shared__ unsigned int xsp[2][132];
  __shared__ unsigned int ysp[2][132];
  __shared__ float red[7][64][9];

  float ca = qa, cb = qb, cc = qc;
  if (first) {
    float tr = 0.f;
#pragma unroll
    for (int q = 0; q < 8; ++q) tr += part[m * 8 + q];
    const float s = 0.15f * sqrtf(tr);     // 1.2 * 2*||C||_F/sqrt(256)
    const float is = 1.f / s, is2 = is * is;
    ca = qa * is;
    cb = qb * is * is2;
    cc = qc * is * is2 * is2;
  }

  if (t < 128) {  // stage 2-row X strip: fp32 + f16 pairs
    const int r = t >> 6, c16 = t & 63;
    const float4 v = *(const float4*)&Xm[(i0 + r) * 256 + c16 * 4];
    *(float4*)&xs[r][c16 * 4] = v;
    xsp[r][2 * c16]     = pkh(v.x, v.y);
    xsp[r][2 * c16 + 1] = pkh(v.z, v.w);
  }
  __syncthreads();

  const int kp0 = h * 16;
  float accY[2][4];
#pragma unroll
  for (int i = 0; i < 2; ++i)
#pragma unroll
    for (int j = 0; j < 4; ++j) accY[i][j] = 0.f;
#pragma unroll 8
  for (int kk = 0; kk < 16; ++kk) {
    const int kp = kp0 + kk;
    const uint4 aw = A4[kp * 64 + u];
    const half2_t b0 = uh(aw.x), b1 = uh(aw.y), b2 = uh(aw.z), b3 = uh(aw.w);
#pragma unroll
    for (int r = 0; r < 2; ++r) {
      const half2_t xp = uh(xsp[r][kp]);
      accY[r][0] = FDOT2(xp, b0, accY[r][0]);
      accY[r][1] = FDOT2(xp, b1, accY[r][1]);
      accY[r][2] = FDOT2(xp, b2, accY[r][2]);
      accY[r][3] = FDOT2(xp, b3, accY[r][3]);
    }
  }
  if (h) {
    float* rr = &red[h - 1][u][0];
#pragma unroll
    for (int i = 0; i < 2; ++i)
#pragma unroll
      for (int j = 0; j < 4; ++j) rr[i * 4 + j] = accY[i][j];
  }
  __syncthreads();
  float yv[2][4];
  if (h == 0) {
#pragma unroll
    for (int i = 0; i < 2; ++i)
#pragma unroll
      for (int j = 0; j < 4; ++j) {
        float s = accY[i][j];
#pragma unroll
        for (int q = 0; q < 7; ++q) s += red[q][u][i * 4 + j];
        yv[i][j] = s;
      }
#pragma unroll
    for (int i = 0; i < 2; ++i) {
      ysp[i][2 * u]     = pkh(yv[i][0], yv[i][1]);
      ysp[i][2 * u + 1] = pkh(yv[i][2], yv[i][3]);
    }
  }
  __syncthreads();

  float accZ[2][4];
#pragma unroll
  for (int i = 0; i < 2; ++i)
#pragma unroll
    for (int j = 0; j < 4; ++j) accZ[i][j] = 0.f;
#pragma unroll 8
  for (int kk = 0; kk < 16; ++kk) {
    const int kp = kp0 + kk;
    const uint4 aw = A4[kp * 64 + u];
    const half2_t b0 = uh(aw.x), b1 = uh(aw.y), b2 = uh(aw.z), b3 = uh(aw.w);
#pragma unroll
    for (int r = 0; r < 2; ++r) {
      const half2_t yp = uh(ysp[r][kp]);
      accZ[r][0] = FDOT2(yp, b0, accZ[r][0]);
      accZ[r][1] = FDOT2(yp, b1, accZ[r][1]);
      accZ[r][2] = FDOT2(yp, b2, accZ[r][2]);
      accZ[r][3] = FDOT2(yp, b3, accZ[r][3]);
    }
  }
  if (h) {
    float* rr = &red[h - 1][u][0];
#pragma unroll
    for (int i = 0; i < 2; ++i)
#pragma unroll
      for (int j = 0; j < 4; ++j) rr[i * 4 + j] = accZ[i][j];
  }
  __syncthreads();
  if (h == 0) {
#pragma unroll
    for (int i = 0; i < 2; ++i) {
      float o[4];
#pragma unroll
      for (int j = 0; j < 4; ++j) {
        float z = accZ[i][j];
#pragma unroll
        for (int q = 0; q < 7; ++q) z += red[q][u][i * 4 + j];
        o[j] = ca * xs[i][u * 4 + j] + cb * yv[i][j] + cc * z;
      }
      *(float4*)&Xo[(i0 + i) * 256 + u * 4] = make_float4(o[0], o[1], o[2], o[3]);
    }
  }
}

// ---------------- NS phase B9 (degree-9 convergent), 2-row strips (grid NM*128) ----------------
__global__ __launch_bounds__(512) void k_pB9(const float* __restrict__ Xs,
                                             const unsigned int* __restrict__ Acp,
                                             float* __restrict__ Xn) {
  const int m = blockIdx.x >> 7, g = blockIdx.x & 127, i0 = g * 2;
  const float* Xm = Xs + (size_t)m * MSZ;
  const uint4* A4 = (const uint4*)(Acp + (size_t)m * (128 * 256));
  float* Xo = Xn + (size_t)m * MSZ;
  const int t = threadIdx.x, h = t >> 6, u = t & 63;
  __shared__ float xs[2][260];
  __shared__ unsigned int buf0[2][132];
  __shared__ unsigned int buf1[2][132];
  __shared__ float red[7][64][9];

  if (t < 128) {
    const int r = t >> 6, c16 = t & 63;
    const float4 v = *(const float4*)&Xm[(i0 + r) * 256 + c16 * 4];
    *(float4*)&xs[r][c16 * 4] = v;
    buf0[r][2 * c16]     = pkh(v.x, v.y);
    buf0[r][2 * c16 + 1] = pkh(v.z, v.w);
  }
  __syncthreads();

  const int kp0 = h * 16;
  float out[2][4];
  if (h == 0) {
#pragma unroll
    for (int i = 0; i < 2; ++i)
#pragma unroll
      for (int j = 0; j < 4; ++j) out[i][j] = D9_0 * xs[i][u * 4 + j];
  }

#pragma unroll
  for (int p = 0; p < 4; ++p) {
    const float cp = (p == 0) ? D9_1 : (p == 1) ? D9_2 : (p == 2) ? D9_3 : D9_4;
    unsigned int (*src)[132] = (p & 1) ? buf1 : buf0;
    unsigned int (*dst)[132] = (p & 1) ? buf0 : buf1;

    float acc[2][4];
#pragma unroll
    for (int i = 0; i < 2; ++i)
#pragma unroll
      for (int j = 0; j < 4; ++j) acc[i][j] = 0.f;
#pragma unroll 8
    for (int kk = 0; kk < 16; ++kk) {
      const int kp = kp0 + kk;
      const uint4 aw = A4[kp * 64 + u];
      const half2_t b0 = uh(aw.x), b1 = uh(aw.y), b2 = uh(aw.z), b3 = uh(aw.w);
#pragma unroll
      for (int r = 0; r < 2; ++r) {
        const half2_t xp = uh(src[r][kp]);
        acc[r][0] = FDOT2(xp, b0, acc[r][0]);
        acc[r][1] = FDOT2(xp, b1, acc[r][1]);
        acc[r][2] = FDOT2(xp, b2, acc[r][2]);
        acc[r][3] = FDOT2(xp, b3, acc[r][3]);
      }
    }
    if (h) {
      float* rr = &red[h - 1][u][0];
#pragma unroll
      for (int i = 0; i < 2; ++i)
#pragma unroll
        for (int j = 0; j < 4; ++j) rr[i * 4 + j] = acc[i][j];
    }
    __syncthreads();
    if (h == 0) {
#pragma unroll
      for (int i = 0; i < 2; ++i) {
        float tv[4];
#pragma unroll
        for (int j = 0; j < 4; ++j) {
          float s = acc[i][j];
#pragma unroll
          for (int q = 0; q < 7; ++q) s += red[q][u][i * 4 + j];
          tv[j] = s;
          out[i][j] += cp * s;
        }
        if (p < 3) {
          dst[i][2 * u]     = pkh(tv[0], tv[1]);
          dst[i][2 * u + 1] = pkh(tv[2], tv[3]);
        }
      }
    }
    __syncthreads();
  }

  if (h == 0) {
#pragma unroll
    for (int i = 0; i < 2; ++i)
      *(float4*)&Xo[(i0 + i) * 256 + u * 4] =
          make_float4(out[i][0], out[i][1], out[i][2], out[i][3]);
  }
}

// ---------------- K4: output assembly ----------------
__global__ __launch_bounds__(256) void k_out(const float* __restrict__ sp,
                                             const float* __restrict__ P,
                                             const int* __restrict__ sel,
                                             float* __restrict__ out) {
  const int t = threadIdx.x;
  if (blockIdx.x < 128) {
    const int b = blockIdx.x;
    __shared__ float hd[256];
    hd[t] = sp[(size_t)b * Kd + t];
    __syncthreads();
    const int s = sel[b];
    if (s < 0) {
      out[(size_t)b * Kd + t] = hd[t];
    } else {
      const float4* prow = (const float4*)(P + (size_t)s * MSZ + t * 256);
      float acc = 0.f;
#pragma unroll 8
      for (int j4 = 0; j4 < 64; ++j4) {
        const float4 p = prow[j4];
        acc += p.x * hd[4 * j4 + 0] + p.y * hd[4 * j4 + 1] +
               p.z * hd[4 * j4 + 2] + p.w * hd[4 * j4 + 3];
      }
      out[(size_t)b * Kd + t] = hd[t] + 0.1f * acc;
    }
  } else {
    const int ci = blockIdx.x - 128;
    const float4* in4 = (const float4*)sp;
    float4* out4 = (float4*)out;
    const int total = Bn * (Kd / 4);
    for (int i = ci * 256 + t; i < total; i += 2048 * 256) {
      const int pos = i & ((Kd / 4) - 1);
      if (pos >= Qd / 4) out4[i] = in4[i];
    }
  }
}

// ---------------- host ----------------
extern "C" void kernel_launch(void* const* d_in, const int* in_sizes, int n_in,
                              void* d_out, int out_size, void* d_ws, size_t ws_size,
                              hipStream_t stream) {
  (void)in_sizes; (void)n_in; (void)out_size; (void)ws_size;
  const float* sp = (const float*)d_in[0];
  const float* W1 = (const float*)d_in[1];
  const float* b1 = (const float*)d_in[2];
  const float* W2 = (const float*)d_in[3];
  const float* b2 = (const float*)d_in[4];
  const float* W3 = (const float*)d_in[5];
  const float* b3 = (const float*)d_in[6];
  const float* ops = (const float*)d_in[7];
  float* out = (float*)d_out;
  float* ws = (float*)d_ws;

  float* h1p  = ws + OFF_H1P;
  float* h1   = ws + OFF_H1;
  int*   sel  = (int*)(ws + OFF_SEL);
  float* part = ws + OFF_PART;
  float* Xa   = ws + OFF_XA;
  float* Xb   = ws + OFF_XB;
  unsigned int* Acp = (unsigned int*)(ws + OFF_ACP);

  k_gemm1<<<NCH, 256, 0, stream>>>(sp, W1, h1p);
  k_red<<<256, 256, 0, stream>>>(h1p, b1, h1);
  k_mlp<<<8, 256, 0, stream>>>(h1, W2, b2, W3, b3, sel);

  // 7 Muon iterations (first folds the 1/s scale), then degree-9 convergent
  k_pA<<<NM * 36, 512, 0, stream>>>(ops, Acp, part);
  k_pB<<<NM * 128, 512, 0, stream>>>(ops, Acp, part, Xa, MA, MB, MC, 1);

  float* X = Xa;
  float* Xn = Xb;
  for (int it = 1; it < 7; ++it) {
    k_pA<<<NM * 36, 512, 0, stream>>>(X, Acp, part);
    k_pB<<<NM * 128, 512, 0, stream>>>(X, Acp, part, Xn, MA, MB, MC, 0);
    float* tmp = X; X = Xn; Xn = tmp;
  }
  k_pA<<<NM * 36, 512, 0, stream>>>(X, Acp, part);
  k_pB9<<<NM * 128, 512, 0, stream>>>(X, Acp, Xn);
  X = Xn;

  k_out<<<128 + 2048, 256, 0, stream>>>(sp, X, sel, out);
}

// Round 17
// 174.211 us; speedup vs baseline: 1.5265x; 1.0957x over previous
//
#include <hip/hip_runtime.h>
#include <math.h>

// ---------------- problem constants ----------------
constexpr int Bn  = 128;
constexpr int Kd  = 65536;    // magnitude dim (phase half of feats is zeros)
constexpr int F1  = 128;
constexpr int F2  = 64;
constexpr int NM  = 3;
constexpr int Qd  = 256;
constexpr int NCH = 256;      // split-K chunks for big GEMM
constexpr int KC  = 256;      // k per chunk
constexpr int MSZ = 256 * 256;

// Muon (growth) quintic Newton-Schulz coefficients
#define MA 3.4445f
#define MB (-4.7750f)
#define MC 2.0315f
// degree-9 convergent NS: x*(315 - 420y + 378y^2 - 180y^3 + 35y^4)/128, y=x^2
#define D9_0 (315.f / 128.f)
#define D9_1 (-420.f / 128.f)
#define D9_2 (378.f / 128.f)
#define D9_3 (-180.f / 128.f)
#define D9_4 (35.f / 128.f)

// ---------------- ws layout (float offsets) ----------------
constexpr size_t OFF_H1P  = 0;                                   // 256*128*128 floats
constexpr size_t OFF_PART = OFF_H1P + (size_t)NCH * Bn * F1;     // 24 -> pad 64
constexpr size_t OFF_XA   = OFF_PART + 64;
constexpr size_t OFF_XB   = OFF_XA + (size_t)NM * MSZ;
constexpr size_t OFF_ACP  = OFF_XB + (size_t)NM * MSZ;           // u32: NM*128*256

// ---------------- f16 helpers (NS chain) ----------------
typedef __fp16 half2_t __attribute__((ext_vector_type(2)));
union HU { half2_t h; unsigned int u; };
__device__ __forceinline__ unsigned int pkh(float x, float y) {
  HU v; v.h = __builtin_amdgcn_cvt_pkrtz(x, y); return v.u;
}
__device__ __forceinline__ half2_t uh(unsigned int u) { HU v; v.u = u; return v.h; }

#if __has_builtin(__builtin_amdgcn_fdot2)
#define FDOT2(a, b, c) __builtin_amdgcn_fdot2((a), (b), (c), false)
#else
#define FDOT2(a, b, c) ((c) + (float)(a)[0] * (float)(b)[0] + (float)(a)[1] * (float)(b)[1])
#endif

// ---------------- bf16 helpers (MFMA GEMM) ----------------
typedef short bf16x8 __attribute__((ext_vector_type(8)));
typedef float f32x4 __attribute__((ext_vector_type(4)));
__device__ __forceinline__ unsigned short bh(float x) {   // RNE fp32 -> bf16
  unsigned int bx = __float_as_uint(x);
  return (unsigned short)((bx + 0x7FFFu + ((bx >> 16) & 1u)) >> 16);
}
__device__ __forceinline__ float bf(unsigned short h) {
  return __uint_as_float((unsigned int)h << 16);
}

// ---------------- K1: split-K magnitude GEMM via bf16-split MFMA ----------------
// 256 blocks x 256 thr; block = k-chunk of 256 (4 subchunks of 64).
__global__ __launch_bounds__(256) void k_gemm1(const float* __restrict__ sp,
                                               const float* __restrict__ W1,
                                               float* __restrict__ h1p) {
  __shared__ short Ah[128][72];
  __shared__ short Al[128][72];
  __shared__ short Bh[128][72];
  __shared__ short Bl[128][72];
  const int t = threadIdx.x;
  const int w = t >> 6, l = t & 63;
  const int l15 = l & 15, lg = l >> 4;
  const int ch = blockIdx.x;
  const size_t k0 = (size_t)ch * KC;
  const int srow = t >> 4;
  const int skq  = (t & 15) * 4;

  f32x4 acc[2][8];
#pragma unroll
  for (int r = 0; r < 2; ++r)
#pragma unroll
    for (int c = 0; c < 8; ++c) acc[r][c] = (f32x4){0.f, 0.f, 0.f, 0.f};

#pragma unroll
  for (int sub = 0; sub < 4; ++sub) {
    __syncthreads();
    const size_t kb = k0 + sub * 64 + skq;
#pragma unroll
    for (int rep = 0; rep < 8; ++rep) {
      const int row = srow + rep * 16;
      const float4 av = *(const float4*)(sp + (size_t)row * Kd + kb);
      const float4 bv = *(const float4*)(W1 + (size_t)row * (2 * Kd) + kb);
      float va[4] = {fabsf(av.x), fabsf(av.y), fabsf(av.z), fabsf(av.w)};
      float vb[4] = {bv.x, bv.y, bv.z, bv.w};
      unsigned short ha[4], la[4], hb[4], lb[4];
#pragma unroll
      for (int e = 0; e < 4; ++e) {
        ha[e] = bh(va[e]); la[e] = bh(va[e] - bf(ha[e]));
        hb[e] = bh(vb[e]); lb[e] = bh(vb[e] - bf(hb[e]));
      }
      *(uint2*)&Ah[row][skq] = make_uint2((unsigned)ha[0] | ((unsigned)ha[1] << 16),
                                          (unsigned)ha[2] | ((unsigned)ha[3] << 16));
      *(uint2*)&Al[row][skq] = make_uint2((unsigned)la[0] | ((unsigned)la[1] << 16),
                                          (unsigned)la[2] | ((unsigned)la[3] << 16));
      *(uint2*)&Bh[row][skq] = make_uint2((unsigned)hb[0] | ((unsigned)hb[1] << 16),
                                          (unsigned)hb[2] | ((unsigned)hb[3] << 16));
      *(uint2*)&Bl[row][skq] = make_uint2((unsigned)lb[0] | ((unsigned)lb[1] << 16),
                                          (unsigned)lb[2] | ((unsigned)lb[3] << 16));
    }
    __syncthreads();
#pragma unroll
    for (int ks = 0; ks < 2; ++ks) {
      const int ko = ks * 32 + lg * 8;
      bf16x8 afh[2], afl[2];
#pragma unroll
      for (int r = 0; r < 2; ++r) {
        const int row = w * 32 + r * 16 + l15;
        afh[r] = *(const bf16x8*)&Ah[row][ko];
        afl[r] = *(const bf16x8*)&Al[row][ko];
      }
#pragma unroll
      for (int c = 0; c < 8; ++c) {
        const int col = c * 16 + l15;
        const bf16x8 bfh = *(const bf16x8*)&Bh[col][ko];
        const bf16x8 bfl = *(const bf16x8*)&Bl[col][ko];
#pragma unroll
        for (int r = 0; r < 2; ++r) {
          acc[r][c] = __builtin_amdgcn_mfma_f32_16x16x32_bf16(afh[r], bfh, acc[r][c], 0, 0, 0);
          acc[r][c] = __builtin_amdgcn_mfma_f32_16x16x32_bf16(afh[r], bfl, acc[r][c], 0, 0, 0);
          acc[r][c] = __builtin_amdgcn_mfma_f32_16x16x32_bf16(afl[r], bfh, acc[r][c], 0, 0, 0);
        }
      }
    }
  }

  float* outp = h1p + (size_t)ch * (Bn * F1);
#pragma unroll
  for (int r = 0; r < 2; ++r)
#pragma unroll
    for (int c = 0; c < 8; ++c) {
      const int col = c * 16 + l15;
#pragma unroll
      for (int reg = 0; reg < 4; ++reg) {
        const int row = w * 32 + r * 16 + lg * 4 + reg;
        outp[row * F1 + col] = acc[r][c][reg];
      }
    }
}

// ---------------- NS phase A: A = X^T X -> f16 colpk (symmetric 32x32 tiles) ----------------
__global__ __launch_bounds__(512) void k_pA(const float* __restrict__ Xs,
                                            unsigned int* __restrict__ Acp,
                                            float* __restrict__ part) {
  const int bid = blockIdx.x;
  const int m = bid / 36;
  int rem = bid % 36;
  int I = 0;
  while (rem >= 8 - I) { rem -= 8 - I; ++I; }
  const int J = I + rem;
  const float* Xm = Xs + (size_t)m * MSZ;
  unsigned int* Am = Acp + (size_t)m * (128 * 256);
  __shared__ float PI[32][260];
  __shared__ float PJb[32][260];
  __shared__ float red[7][64][17];
  __shared__ float tr8[8];
  float (*PJ)[260] = (I == J) ? PI : PJb;
  const int t = threadIdx.x;

#pragma unroll
  for (int it = 0; it < 4; ++it) {
    const int task = it * 512 + t;
    const int k = task >> 3, c4 = task & 7;
    const float4 vI = *(const float4*)&Xm[k * 256 + I * 32 + c4 * 4];
#pragma unroll
    for (int e = 0; e < 4; ++e) PI[c4 * 4 + e][k] = (&vI.x)[e];
    if (I != J) {
      const float4 vJ = *(const float4*)&Xm[k * 256 + J * 32 + c4 * 4];
#pragma unroll
      for (int e = 0; e < 4; ++e) PJb[c4 * 4 + e][k] = (&vJ.x)[e];
    }
  }
  __syncthreads();

  const int h = t >> 6, u = t & 63, ur = u >> 3, uc = u & 7;
  float a[4][4];
#pragma unroll
  for (int i = 0; i < 4; ++i)
#pragma unroll
    for (int j = 0; j < 4; ++j) a[i][j] = 0.f;

  const int kb = h * 32;
#pragma unroll 8
  for (int kk = 0; kk < 32; ++kk) {
    const int k = kb + kk;
    float xi[4], xj[4];
#pragma unroll
    for (int i = 0; i < 4; ++i) xi[i] = PI[ur * 4 + i][k];
#pragma unroll
    for (int j = 0; j < 4; ++j) xj[j] = PJ[uc * 4 + j][k];
#pragma unroll
    for (int i = 0; i < 4; ++i)
#pragma unroll
      for (int j = 0; j < 4; ++j) a[i][j] += xi[i] * xj[j];
  }
  if (h) {
    float* rr = &red[h - 1][u][0];
#pragma unroll
    for (int i = 0; i < 4; ++i)
#pragma unroll
      for (int j = 0; j < 4; ++j) rr[i * 4 + j] = a[i][j];
  }
  __syncthreads();
  if (h == 0) {
#pragma unroll
    for (int i = 0; i < 4; ++i)
#pragma unroll
      for (int j = 0; j < 4; ++j) {
        float s = a[i][j];
#pragma unroll
        for (int q = 0; q < 7; ++q) s += red[q][u][i * 4 + j];
        a[i][j] = s;
      }
    const int gr = I * 32 + ur * 4, gc = J * 32 + uc * 4;
    {
      const int kp = gr >> 1;
      *(uint4*)&Am[kp * 256 + gc] =
          make_uint4(pkh(a[0][0], a[1][0]), pkh(a[0][1], a[1][1]),
                     pkh(a[0][2], a[1][2]), pkh(a[0][3], a[1][3]));
      *(uint4*)&Am[(kp + 1) * 256 + gc] =
          make_uint4(pkh(a[2][0], a[3][0]), pkh(a[2][1], a[3][1]),
                     pkh(a[2][2], a[3][2]), pkh(a[2][3], a[3][3]));
    }
    if (I != J) {
      const int kp = gc >> 1;
      *(uint4*)&Am[kp * 256 + gr] =
          make_uint4(pkh(a[0][0], a[0][1]), pkh(a[1][0], a[1][1]),
                     pkh(a[2][0], a[2][1]), pkh(a[3][0], a[3][1]));
      *(uint4*)&Am[(kp + 1) * 256 + gr] =
          make_uint4(pkh(a[0][2], a[0][3]), pkh(a[1][2], a[1][3]),
                     pkh(a[2][2], a[2][3]), pkh(a[3][2], a[3][3]));
    } else if (ur == uc) {
      tr8[ur] = a[0][0] + a[1][1] + a[2][2] + a[3][3];
    }
  }
  if (I == J) {
    __syncthreads();
    if (t == 0) {
      float s = 0.f;
#pragma unroll
      for (int q = 0; q < 8; ++q) s += tr8[q];
      part[m * 8 + I] = s;
    }
  }
}

// ---------------- NS phase B (Muon quintic), 2-row strips (grid NM*128) ----------------
__global__ __launch_bounds__(512) void k_pB(const float* __restrict__ Xs,
                                            const unsigned int* __restrict__ Acp,
                                            const float* __restrict__ part,
                                            float* __restrict__ Xn,
                                            const float qa, const float qb, const float qc,
                                            const int first) {
  const int m = blockIdx.x >> 7, g = blockIdx.x & 127, i0 = g * 2;
  const float* Xm = Xs + (size_t)m * MSZ;
  const uint4* A4 = (const uint4*)(Acp + (size_t)m * (128 * 256));
  float* Xo = Xn + (size_t)m * MSZ;
  const int t = threadIdx.x, h = t >> 6, u = t & 63;
  __shared__ float xs[2][260];
  __shared__ unsigned int xsp[2][132];
  __shared__ unsigned int ysp[2][132];
  __shared__ float red[7][64][9];

  float ca = qa, cb = qb, cc = qc;
  if (first) {
    float tr = 0.f;
#pragma unroll
    for (int q = 0; q < 8; ++q) tr += part[m * 8 + q];
    const float s = 0.15f * sqrtf(tr);     // 1.2 * 2*||C||_F/sqrt(256)
    const float is = 1.f / s, is2 = is * is;
    ca = qa * is;
    cb = qb * is * is2;
    cc = qc * is * is2 * is2;
  }

  if (t < 128) {  // stage 2-row X strip: fp32 + f16 pairs
    const int r = t >> 6, c16 = t & 63;
    const float4 v = *(const float4*)&Xm[(i0 + r) * 256 + c16 * 4];
    *(float4*)&xs[r][c16 * 4] = v;
    xsp[r][2 * c16]     = pkh(v.x, v.y);
    xsp[r][2 * c16 + 1] = pkh(v.z, v.w);
  }
  __syncthreads();

  const int kp0 = h * 16;
  float accY[2][4];
#pragma unroll
  for (int i = 0; i < 2; ++i)
#pragma unroll
    for (int j = 0; j < 4; ++j) accY[i][j] = 0.f;
#pragma unroll 8
  for (int kk = 0; kk < 16; ++kk) {
    const int kp = kp0 + kk;
    const uint4 aw = A4[kp * 64 + u];
    const half2_t b0 = uh(aw.x), b1 = uh(aw.y), b2 = uh(aw.z), b3 = uh(aw.w);
#pragma unroll
    for (int r = 0; r < 2; ++r) {
      const half2_t xp = uh(xsp[r][kp]);
      accY[r][0] = FDOT2(xp, b0, accY[r][0]);
      accY[r][1] = FDOT2(xp, b1, accY[r][1]);
      accY[r][2] = FDOT2(xp, b2, accY[r][2]);
      accY[r][3] = FDOT2(xp, b3, accY[r][3]);
    }
  }
  if (h) {
    float* rr = &red[h - 1][u][0];
#pragma unroll
    for (int i = 0; i < 2; ++i)
#pragma unroll
      for (int j = 0; j < 4; ++j) rr[i * 4 + j] = accY[i][j];
  }
  __syncthreads();
  float yv[2][4];
  if (h == 0) {
#pragma unroll
    for (int i = 0; i < 2; ++i)
#pragma unroll
      for (int j = 0; j < 4; ++j) {
        float s = accY[i][j];
#pragma unroll
        for (int q = 0; q < 7; ++q) s += red[q][u][i * 4 + j];
        yv[i][j] = s;
      }
#pragma unroll
    for (int i = 0; i < 2; ++i) {
      ysp[i][2 * u]     = pkh(yv[i][0], yv[i][1]);
      ysp[i][2 * u + 1] = pkh(yv[i][2], yv[i][3]);
    }
  }
  __syncthreads();

  float accZ[2][4];
#pragma unroll
  for (int i = 0; i < 2; ++i)
#pragma unroll
    for (int j = 0; j < 4; ++j) accZ[i][j] = 0.f;
#pragma unroll 8
  for (int kk = 0; kk < 16; ++kk) {
    const int kp = kp0 + kk;
    const uint4 aw = A4[kp * 64 + u];
    const half2_t b0 = uh(aw.x), b1 = uh(aw.y), b2 = uh(aw.z), b3 = uh(aw.w);
#pragma unroll
    for (int r = 0; r < 2; ++r) {
      const half2_t yp = uh(ysp[r][kp]);
      accZ[r][0] = FDOT2(yp, b0, accZ[r][0]);
      accZ[r][1] = FDOT2(yp, b1, accZ[r][1]);
      accZ[r][2] = FDOT2(yp, b2, accZ[r][2]);
      accZ[r][3] = FDOT2(yp, b3, accZ[r][3]);
    }
  }
  if (h) {
    float* rr = &red[h - 1][u][0];
#pragma unroll
    for (int i = 0; i < 2; ++i)
#pragma unroll
      for (int j = 0; j < 4; ++j) rr[i * 4 + j] = accZ[i][j];
  }
  __syncthreads();
  if (h == 0) {
#pragma unroll
    for (int i = 0; i < 2; ++i) {
      float o[4];
#pragma unroll
      for (int j = 0; j < 4; ++j) {
        float z = accZ[i][j];
#pragma unroll
        for (int q = 0; q < 7; ++q) z += red[q][u][i * 4 + j];
        o[j] = ca * xs[i][u * 4 + j] + cb * yv[i][j] + cc * z;
      }
      *(float4*)&Xo[(i0 + i) * 256 + u * 4] = make_float4(o[0], o[1], o[2], o[3]);
    }
  }
}

// ---------------- NS phase B9 (degree-9 convergent), 2-row strips (grid NM*128) ----------------
__global__ __launch_bounds__(512) void k_pB9(const float* __restrict__ Xs,
                                             const unsigned int* __restrict__ Acp,
                                             float* __restrict__ Xn) {
  const int m = blockIdx.x >> 7, g = blockIdx.x & 127, i0 = g * 2;
  const float* Xm = Xs + (size_t)m * MSZ;
  const uint4* A4 = (const uint4*)(Acp + (size_t)m * (128 * 256));
  float* Xo = Xn + (size_t)m * MSZ;
  const int t = threadIdx.x, h = t >> 6, u = t & 63;
  __shared__ float xs[2][260];
  __shared__ unsigned int buf0[2][132];
  __shared__ unsigned int buf1[2][132];
  __shared__ float red[7][64][9];

  if (t < 128) {
    const int r = t >> 6, c16 = t & 63;
    const float4 v = *(const float4*)&Xm[(i0 + r) * 256 + c16 * 4];
    *(float4*)&xs[r][c16 * 4] = v;
    buf0[r][2 * c16]     = pkh(v.x, v.y);
    buf0[r][2 * c16 + 1] = pkh(v.z, v.w);
  }
  __syncthreads();

  const int kp0 = h * 16;
  float out[2][4];
  if (h == 0) {
#pragma unroll
    for (int i = 0; i < 2; ++i)
#pragma unroll
      for (int j = 0; j < 4; ++j) out[i][j] = D9_0 * xs[i][u * 4 + j];
  }

#pragma unroll
  for (int p = 0; p < 4; ++p) {
    const float cp = (p == 0) ? D9_1 : (p == 1) ? D9_2 : (p == 2) ? D9_3 : D9_4;
    unsigned int (*src)[132] = (p & 1) ? buf1 : buf0;
    unsigned int (*dst)[132] = (p & 1) ? buf0 : buf1;

    float acc[2][4];
#pragma unroll
    for (int i = 0; i < 2; ++i)
#pragma unroll
      for (int j = 0; j < 4; ++j) acc[i][j] = 0.f;
#pragma unroll 8
    for (int kk = 0; kk < 16; ++kk) {
      const int kp = kp0 + kk;
      const uint4 aw = A4[kp * 64 + u];
      const half2_t b0 = uh(aw.x), b1 = uh(aw.y), b2 = uh(aw.z), b3 = uh(aw.w);
#pragma unroll
      for (int r = 0; r < 2; ++r) {
        const half2_t xp = uh(src[r][kp]);
        acc[r][0] = FDOT2(xp, b0, acc[r][0]);
        acc[r][1] = FDOT2(xp, b1, acc[r][1]);
        acc[r][2] = FDOT2(xp, b2, acc[r][2]);
        acc[r][3] = FDOT2(xp, b3, acc[r][3]);
      }
    }
    if (h) {
      float* rr = &red[h - 1][u][0];
#pragma unroll
      for (int i = 0; i < 2; ++i)
#pragma unroll
        for (int j = 0; j < 4; ++j) rr[i * 4 + j] = acc[i][j];
    }
    __syncthreads();
    if (h == 0) {
#pragma unroll
      for (int i = 0; i < 2; ++i) {
        float tv[4];
#pragma unroll
        for (int j = 0; j < 4; ++j) {
          float s = acc[i][j];
#pragma unroll
          for (int q = 0; q < 7; ++q) s += red[q][u][i * 4 + j];
          tv[j] = s;
          out[i][j] += cp * s;
        }
        if (p < 3) {
          dst[i][2 * u]     = pkh(tv[0], tv[1]);
          dst[i][2 * u + 1] = pkh(tv[2], tv[3]);
        }
      }
    }
    __syncthreads();
  }

  if (h == 0) {
#pragma unroll
    for (int i = 0; i < 2; ++i)
      *(float4*)&Xo[(i0 + i) * 256 + u * 4] =
          make_float4(out[i][0], out[i][1], out[i][2], out[i][3]);
  }
}

// ---------------- K4: fused h1-reduce + MLP + selection + output assembly ----------------
// blocks 0..127: per-batch head path; blocks 128..2175: float4 tail copy.
__global__ __launch_bounds__(256) void k_out(const float* __restrict__ sp,
                                             const float* __restrict__ h1p,
                                             const float* __restrict__ b1,
                                             const float* __restrict__ W2,
                                             const float* __restrict__ b2,
                                             const float* __restrict__ W3,
                                             const float* __restrict__ b3,
                                             const float* __restrict__ P,
                                             float* __restrict__ out) {
  const int t = threadIdx.x;
  if (blockIdx.x < 128) {
    const int b = blockIdx.x;
    __shared__ float hd[256];
    __shared__ float h1s[128];
    __shared__ float h2s[64];
    __shared__ int sel_s;
    hd[t] = sp[(size_t)b * Kd + t];
    if (t < 128) {  // h1[b][t] = relu(sum_c h1p[c][b][t] + b1[t]), fp64 sum
      double s = 0.0;
      const float* hp = h1p + b * F1 + t;
#pragma unroll 8
      for (int c = 0; c < NCH; ++c) s += (double)hp[(size_t)c * (Bn * F1)];
      h1s[t] = fmaxf((float)s + b1[t], 0.f);
    }
    __syncthreads();
    if (t < 64) {   // h2 = relu(W2 h1 + b2), fp32 (same as prior k_mlp)
      const float* wr = W2 + t * F1;
      float s = b2[t];
      for (int k = 0; k < F1; ++k) s += h1s[k] * wr[k];
      h2s[t] = fmaxf(s, 0.f);
    }
    __syncthreads();
    if (t == 0) {   // syndrome in fp64, strict-> argmax (first-max ties)
      float best = -1.f;
      int bi = 0;
      bool needed = false;
      for (int j = 0; j < 8; ++j) {
        double s = (double)b3[j];
        const float* wr = W3 + j * F2;
        for (int k = 0; k < F2; ++k) s += (double)h2s[k] * (double)wr[k];
        const float a = fabsf((float)s);
        if (a > 1e-4f) needed = true;
        if (a > best) { best = a; bi = j; }
      }
      sel_s = needed ? (bi % NM) : -1;
    }
    __syncthreads();
    const int s = sel_s;
    if (s < 0) {
      out[(size_t)b * Kd + t] = hd[t];
    } else {
      const float4* prow = (const float4*)(P + (size_t)s * MSZ + t * 256);
      float acc = 0.f;
#pragma unroll 8
      for (int j4 = 0; j4 < 64; ++j4) {
        const float4 p = prow[j4];
        acc += p.x * hd[4 * j4 + 0] + p.y * hd[4 * j4 + 1] +
               p.z * hd[4 * j4 + 2] + p.w * hd[4 * j4 + 3];
      }
      out[(size_t)b * Kd + t] = hd[t] + 0.1f * acc;
    }
  } else {
    const int ci = blockIdx.x - 128;
    const float4* in4 = (const float4*)sp;
    float4* out4 = (float4*)out;
    const int total = Bn * (Kd / 4);
    for (int i = ci * 256 + t; i < total; i += 2048 * 256) {
      const int pos = i & ((Kd / 4) - 1);
      if (pos >= Qd / 4) out4[i] = in4[i];
    }
  }
}

// ---------------- host ----------------
extern "C" void kernel_launch(void* const* d_in, const int* in_sizes, int n_in,
                              void* d_out, int out_size, void* d_ws, size_t ws_size,
                              hipStream_t stream) {
  (void)in_sizes; (void)n_in; (void)out_size; (void)ws_size;
  const float* sp = (const float*)d_in[0];
  const float* W1 = (const float*)d_in[1];
  const float* b1 = (const float*)d_in[2];
  const float* W2 = (const float*)d_in[3];
  const float* b2 = (const float*)d_in[4];
  const float* W3 = (const float*)d_in[5];
  const float* b3 = (const float*)d_in[6];
  const float* ops = (const float*)d_in[7];
  float* out = (float*)d_out;
  float* ws = (float*)d_ws;

  float* h1p  = ws + OFF_H1P;
  float* part = ws + OFF_PART;
  float* Xa   = ws + OFF_XA;
  float* Xb   = ws + OFF_XB;
  unsigned int* Acp = (unsigned int*)(ws + OFF_ACP);

  k_gemm1<<<NCH, 256, 0, stream>>>(sp, W1, h1p);

  // 7 Muon iterations (first folds the 1/s scale), then degree-9 convergent
  k_pA<<<NM * 36, 512, 0, stream>>>(ops, Acp, part);
  k_pB<<<NM * 128, 512, 0, stream>>>(ops, Acp, part, Xa, MA, MB, MC, 1);

  float* X = Xa;
  float* Xn = Xb;
  for (int it = 1; it < 7; ++it) {
    k_pA<<<NM * 36, 512, 0, stream>>>(X, Acp, part);
    k_pB<<<NM * 128, 512, 0, stream>>>(X, Acp, part, Xn, MA, MB, MC, 0);
    float* tmp = X; X = Xn; Xn = tmp;
  }
  k_pA<<<NM * 36, 512, 0, stream>>>(X, Acp, part);
  k_pB9<<<NM * 128, 512, 0, stream>>>(X, Acp, Xn);
  X = Xn;

  k_out<<<128 + 2048, 256, 0, stream>>>(sp, h1p, b1, W2, b2, W3, b3, X, out);
}

// Round 18
// 162.770 us; speedup vs baseline: 1.6338x; 1.0703x over previous
//
#include <hip/hip_runtime.h>
#include <math.h>

// ---------------- problem constants ----------------
constexpr int Bn  = 128;
constexpr int Kd  = 65536;    // magnitude dim (phase half of feats is zeros)
constexpr int F1  = 128;
constexpr int F2  = 64;
constexpr int NM  = 3;
constexpr int Qd  = 256;
constexpr int NCH = 256;      // split-K chunks for big GEMM
constexpr int KC  = 256;      // k per chunk
constexpr int MSZ = 256 * 256;

// Muon (growth) quintic Newton-Schulz coefficients
#define MA 3.4445f
#define MB (-4.7750f)
#define MC 2.0315f
// degree-9 convergent NS: x*(315 - 420y + 378y^2 - 180y^3 + 35y^4)/128, y=x^2
#define D9_0 (315.f / 128.f)
#define D9_1 (-420.f / 128.f)
#define D9_2 (378.f / 128.f)
#define D9_3 (-180.f / 128.f)
#define D9_4 (35.f / 128.f)

// ---------------- ws layout (float offsets) ----------------
constexpr size_t OFF_H1P  = 0;                                   // 256*128*128 floats
constexpr size_t OFF_PART = OFF_H1P + (size_t)NCH * Bn * F1;     // 24 -> pad 64
constexpr size_t OFF_XA   = OFF_PART + 64;
constexpr size_t OFF_XB   = OFF_XA + (size_t)NM * MSZ;
constexpr size_t OFF_ACP  = OFF_XB + (size_t)NM * MSZ;           // u32: NM*128*256

// ---------------- f16 helpers (NS chain) ----------------
typedef __fp16 half2_t __attribute__((ext_vector_type(2)));
union HU { half2_t h; unsigned int u; };
__device__ __forceinline__ unsigned int pkh(float x, float y) {
  HU v; v.h = __builtin_amdgcn_cvt_pkrtz(x, y); return v.u;
}
__device__ __forceinline__ half2_t uh(unsigned int u) { HU v; v.u = u; return v.h; }

#if __has_builtin(__builtin_amdgcn_fdot2)
#define FDOT2(a, b, c) __builtin_amdgcn_fdot2((a), (b), (c), false)
#else
#define FDOT2(a, b, c) ((c) + (float)(a)[0] * (float)(b)[0] + (float)(a)[1] * (float)(b)[1])
#endif

// ---------------- bf16 helpers (MFMA GEMM) ----------------
typedef short bf16x8 __attribute__((ext_vector_type(8)));
typedef float f32x4 __attribute__((ext_vector_type(4)));
__device__ __forceinline__ unsigned short bh(float x) {   // RNE fp32 -> bf16
  unsigned int bx = __float_as_uint(x);
  return (unsigned short)((bx + 0x7FFFu + ((bx >> 16) & 1u)) >> 16);
}
__device__ __forceinline__ float bf(unsigned short h) {
  return __uint_as_float((unsigned int)h << 16);
}

// ---------------- K1: split-K magnitude GEMM via bf16-split MFMA ----------------
// 256 blocks x 256 thr; block = k-chunk of 256 (4 subchunks of 64).
__global__ __launch_bounds__(256) void k_gemm1(const float* __restrict__ sp,
                                               const float* __restrict__ W1,
                                               float* __restrict__ h1p) {
  __shared__ short Ah[128][72];
  __shared__ short Al[128][72];
  __shared__ short Bh[128][72];
  __shared__ short Bl[128][72];
  const int t = threadIdx.x;
  const int w = t >> 6, l = t & 63;
  const int l15 = l & 15, lg = l >> 4;
  const int ch = blockIdx.x;
  const size_t k0 = (size_t)ch * KC;
  const int srow = t >> 4;
  const int skq  = (t & 15) * 4;

  f32x4 acc[2][8];
#pragma unroll
  for (int r = 0; r < 2; ++r)
#pragma unroll
    for (int c = 0; c < 8; ++c) acc[r][c] = (f32x4){0.f, 0.f, 0.f, 0.f};

#pragma unroll
  for (int sub = 0; sub < 4; ++sub) {
    __syncthreads();
    const size_t kb = k0 + sub * 64 + skq;
#pragma unroll
    for (int rep = 0; rep < 8; ++rep) {
      const int row = srow + rep * 16;
      const float4 av = *(const float4*)(sp + (size_t)row * Kd + kb);
      const float4 bv = *(const float4*)(W1 + (size_t)row * (2 * Kd) + kb);
      float va[4] = {fabsf(av.x), fabsf(av.y), fabsf(av.z), fabsf(av.w)};
      float vb[4] = {bv.x, bv.y, bv.z, bv.w};
      unsigned short ha[4], la[4], hb[4], lb[4];
#pragma unroll
      for (int e = 0; e < 4; ++e) {
        ha[e] = bh(va[e]); la[e] = bh(va[e] - bf(ha[e]));
        hb[e] = bh(vb[e]); lb[e] = bh(vb[e] - bf(hb[e]));
      }
      *(uint2*)&Ah[row][skq] = make_uint2((unsigned)ha[0] | ((unsigned)ha[1] << 16),
                                          (unsigned)ha[2] | ((unsigned)ha[3] << 16));
      *(uint2*)&Al[row][skq] = make_uint2((unsigned)la[0] | ((unsigned)la[1] << 16),
                                          (unsigned)la[2] | ((unsigned)la[3] << 16));
      *(uint2*)&Bh[row][skq] = make_uint2((unsigned)hb[0] | ((unsigned)hb[1] << 16),
                                          (unsigned)hb[2] | ((unsigned)hb[3] << 16));
      *(uint2*)&Bl[row][skq] = make_uint2((unsigned)lb[0] | ((unsigned)lb[1] << 16),
                                          (unsigned)lb[2] | ((unsigned)lb[3] << 16));
    }
    __syncthreads();
#pragma unroll
    for (int ks = 0; ks < 2; ++ks) {
      const int ko = ks * 32 + lg * 8;
      bf16x8 afh[2], afl[2];
#pragma unroll
      for (int r = 0; r < 2; ++r) {
        const int row = w * 32 + r * 16 + l15;
        afh[r] = *(const bf16x8*)&Ah[row][ko];
        afl[r] = *(const bf16x8*)&Al[row][ko];
      }
#pragma unroll
      for (int c = 0; c < 8; ++c) {
        const int col = c * 16 + l15;
        const bf16x8 bfh = *(const bf16x8*)&Bh[col][ko];
        const bf16x8 bfl = *(const bf16x8*)&Bl[col][ko];
#pragma unroll
        for (int r = 0; r < 2; ++r) {
          acc[r][c] = __builtin_amdgcn_mfma_f32_16x16x32_bf16(afh[r], bfh, acc[r][c], 0, 0, 0);
          acc[r][c] = __builtin_amdgcn_mfma_f32_16x16x32_bf16(afh[r], bfl, acc[r][c], 0, 0, 0);
          acc[r][c] = __builtin_amdgcn_mfma_f32_16x16x32_bf16(afl[r], bfh, acc[r][c], 0, 0, 0);
        }
      }
    }
  }

  float* outp = h1p + (size_t)ch * (Bn * F1);
#pragma unroll
  for (int r = 0; r < 2; ++r)
#pragma unroll
    for (int c = 0; c < 8; ++c) {
      const int col = c * 16 + l15;
#pragma unroll
      for (int reg = 0; reg < 4; ++reg) {
        const int row = w * 32 + r * 16 + lg * 4 + reg;
        outp[row * F1 + col] = acc[r][c][reg];
      }
    }
}

// ---------------- NS phase A: A = X^T X -> f16 colpk (symmetric 32x32 tiles) ----------------
// [k][c] LDS layout (pitch 36): staging and inner loop use b128 LDS ops.
__global__ __launch_bounds__(512) void k_pA(const float* __restrict__ Xs,
                                            unsigned int* __restrict__ Acp,
                                            float* __restrict__ part) {
  const int bid = blockIdx.x;
  const int m = bid / 36;
  int rem = bid % 36;
  int I = 0;
  while (rem >= 8 - I) { rem -= 8 - I; ++I; }
  const int J = I + rem;
  const float* Xm = Xs + (size_t)m * MSZ;
  unsigned int* Am = Acp + (size_t)m * (128 * 256);
  __shared__ float PI[256][36];
  __shared__ float PJb[256][36];
  __shared__ float red[7][64][20];
  __shared__ float tr8[8];
  float (*PJ)[36] = (I == J) ? PI : PJb;
  const int t = threadIdx.x;

#pragma unroll
  for (int it = 0; it < 4; ++it) {
    const int task = it * 512 + t;
    const int k = task >> 3, c4 = task & 7;
    const float4 vI = *(const float4*)&Xm[k * 256 + I * 32 + c4 * 4];
    *(float4*)&PI[k][c4 * 4] = vI;
    if (I != J) {
      const float4 vJ = *(const float4*)&Xm[k * 256 + J * 32 + c4 * 4];
      *(float4*)&PJb[k][c4 * 4] = vJ;
    }
  }
  __syncthreads();

  const int h = t >> 6, u = t & 63, ur = u >> 3, uc = u & 7;
  float a[4][4];
#pragma unroll
  for (int i = 0; i < 4; ++i)
#pragma unroll
    for (int j = 0; j < 4; ++j) a[i][j] = 0.f;

  const int kb = h * 32;
#pragma unroll 8
  for (int kk = 0; kk < 32; ++kk) {
    const int k = kb + kk;
    const float4 xi4 = *(const float4*)&PI[k][ur * 4];
    const float4 xj4 = *(const float4*)&PJ[k][uc * 4];
    const float xi[4] = {xi4.x, xi4.y, xi4.z, xi4.w};
    const float xj[4] = {xj4.x, xj4.y, xj4.z, xj4.w};
#pragma unroll
    for (int i = 0; i < 4; ++i)
#pragma unroll
      for (int j = 0; j < 4; ++j) a[i][j] += xi[i] * xj[j];
  }
  if (h) {
    float* rr = &red[h - 1][u][0];
#pragma unroll
    for (int i = 0; i < 4; ++i)
      *(float4*)&rr[i * 4] = make_float4(a[i][0], a[i][1], a[i][2], a[i][3]);
  }
  __syncthreads();
  if (h == 0) {
#pragma unroll
    for (int i = 0; i < 4; ++i)
#pragma unroll
      for (int j = 0; j < 4; ++j) {
        float s = a[i][j];
#pragma unroll
        for (int q = 0; q < 7; ++q) s += red[q][u][i * 4 + j];
        a[i][j] = s;
      }
    const int gr = I * 32 + ur * 4, gc = J * 32 + uc * 4;
    {
      const int kp = gr >> 1;
      *(uint4*)&Am[kp * 256 + gc] =
          make_uint4(pkh(a[0][0], a[1][0]), pkh(a[0][1], a[1][1]),
                     pkh(a[0][2], a[1][2]), pkh(a[0][3], a[1][3]));
      *(uint4*)&Am[(kp + 1) * 256 + gc] =
          make_uint4(pkh(a[2][0], a[3][0]), pkh(a[2][1], a[3][1]),
                     pkh(a[2][2], a[3][2]), pkh(a[2][3], a[3][3]));
    }
    if (I != J) {
      const int kp = gc >> 1;
      *(uint4*)&Am[kp * 256 + gr] =
          make_uint4(pkh(a[0][0], a[0][1]), pkh(a[1][0], a[1][1]),
                     pkh(a[2][0], a[2][1]), pkh(a[3][0], a[3][1]));
      *(uint4*)&Am[(kp + 1) * 256 + gr] =
          make_uint4(pkh(a[0][2], a[0][3]), pkh(a[1][2], a[1][3]),
                     pkh(a[2][2], a[2][3]), pkh(a[3][2], a[3][3]));
    } else if (ur == uc) {
      tr8[ur] = a[0][0] + a[1][1] + a[2][2] + a[3][3];
    }
  }
  if (I == J) {
    __syncthreads();
    if (t == 0) {
      float s = 0.f;
#pragma unroll
      for (int q = 0; q < 8; ++q) s += tr8[q];
      part[m * 8 + I] = s;
    }
  }
}

// ---------------- NS phase B (Muon quintic), 2-row strips (grid NM*128) ----------------
__global__ __launch_bounds__(512) void k_pB(const float* __restrict__ Xs,
                                            const unsigned int* __restrict__ Acp,
                                            const float* __restrict__ part,
                                            float* __restrict__ Xn,
                                            const float qa, const float qb, const float qc,
                                            const int first) {
  const int m = blockIdx.x >> 7, g = blockIdx.x & 127, i0 = g * 2;
  const float* Xm = Xs + (size_t)m * MSZ;
  const uint4* A4 = (const uint4*)(Acp + (size_t)m * (128 * 256));
  float* Xo = Xn + (size_t)m * MSZ;
  const int t = threadIdx.x, h = t >> 6, u = t & 63;
  __shared__ float xs[2][260];
  __shared__ unsigned int xsp[2][132];
  __shared__ unsigned int ysp[2][132];
  __shared__ float red[7][64][9];

  float ca = qa, cb = qb, cc = qc;
  if (first) {
    float tr = 0.f;
#pragma unroll
    for (int q = 0; q < 8; ++q) tr += part[m * 8 + q];
    const float s = 0.15f * sqrtf(tr);     // 1.2 * 2*||C||_F/sqrt(256)
    const float is = 1.f / s, is2 = is * is;
    ca = qa * is;
    cb = qb * is * is2;
    cc = qc * is * is2 * is2;
  }

  if (t < 128) {  // stage 2-row X strip: fp32 + f16 pairs
    const int r = t >> 6, c16 = t & 63;
    const float4 v = *(const float4*)&Xm[(i0 + r) * 256 + c16 * 4];
    *(float4*)&xs[r][c16 * 4] = v;
    xsp[r][2 * c16]     = pkh(v.x, v.y);
    xsp[r][2 * c16 + 1] = pkh(v.z, v.w);
  }
  __syncthreads();

  const int kp0 = h * 16;
  float accY[2][4];
#pragma unroll
  for (int i = 0; i < 2; ++i)
#pragma unroll
    for (int j = 0; j < 4; ++j) accY[i][j] = 0.f;
#pragma unroll 8
  for (int kk = 0; kk < 16; ++kk) {
    const int kp = kp0 + kk;
    const uint4 aw = A4[kp * 64 + u];
    const half2_t b0 = uh(aw.x), b1 = uh(aw.y), b2 = uh(aw.z), b3 = uh(aw.w);
#pragma unroll
    for (int r = 0; r < 2; ++r) {
      const half2_t xp = uh(xsp[r][kp]);
      accY[r][0] = FDOT2(xp, b0, accY[r][0]);
      accY[r][1] = FDOT2(xp, b1, accY[r][1]);
      accY[r][2] = FDOT2(xp, b2, accY[r][2]);
      accY[r][3] = FDOT2(xp, b3, accY[r][3]);
    }
  }
  if (h) {
    float* rr = &red[h - 1][u][0];
#pragma unroll
    for (int i = 0; i < 2; ++i)
#pragma unroll
      for (int j = 0; j < 4; ++j) rr[i * 4 + j] = accY[i][j];
  }
  __syncthreads();
  float yv[2][4];
  if (h == 0) {
#pragma unroll
    for (int i = 0; i < 2; ++i)
#pragma unroll
      for (int j = 0; j < 4; ++j) {
        float s = accY[i][j];
#pragma unroll
        for (int q = 0; q < 7; ++q) s += red[q][u][i * 4 + j];
        yv[i][j] = s;
      }
#pragma unroll
    for (int i = 0; i < 2; ++i) {
      ysp[i][2 * u]     = pkh(yv[i][0], yv[i][1]);
      ysp[i][2 * u + 1] = pkh(yv[i][2], yv[i][3]);
    }
  }
  __syncthreads();

  float accZ[2][4];
#pragma unroll
  for (int i = 0; i < 2; ++i)
#pragma unroll
    for (int j = 0; j < 4; ++j) accZ[i][j] = 0.f;
#pragma unroll 8
  for (int kk = 0; kk < 16; ++kk) {
    const int kp = kp0 + kk;
    const uint4 aw = A4[kp * 64 + u];
    const half2_t b0 = uh(aw.x), b1 = uh(aw.y), b2 = uh(aw.z), b3 = uh(aw.w);
#pragma unroll
    for (int r = 0; r < 2; ++r) {
      const half2_t yp = uh(ysp[r][kp]);
      accZ[r][0] = FDOT2(yp, b0, accZ[r][0]);
      accZ[r][1] = FDOT2(yp, b1, accZ[r][1]);
      accZ[r][2] = FDOT2(yp, b2, accZ[r][2]);
      accZ[r][3] = FDOT2(yp, b3, accZ[r][3]);
    }
  }
  if (h) {
    float* rr = &red[h - 1][u][0];
#pragma unroll
    for (int i = 0; i < 2; ++i)
#pragma unroll
      for (int j = 0; j < 4; ++j) rr[i * 4 + j] = accZ[i][j];
  }
  __syncthreads();
  if (h == 0) {
#pragma unroll
    for (int i = 0; i < 2; ++i) {
      float o[4];
#pragma unroll
      for (int j = 0; j < 4; ++j) {
        float z = accZ[i][j];
#pragma unroll
        for (int q = 0; q < 7; ++q) z += red[q][u][i * 4 + j];
        o[j] = ca * xs[i][u * 4 + j] + cb * yv[i][j] + cc * z;
      }
      *(float4*)&Xo[(i0 + i) * 256 + u * 4] = make_float4(o[0], o[1], o[2], o[3]);
    }
  }
}

// ---------------- NS phase B9 (degree-9 convergent), 2-row strips (grid NM*128) ----------------
__global__ __launch_bounds__(512) void k_pB9(const float* __restrict__ Xs,
                                             const unsigned int* __restrict__ Acp,
                                             float* __restrict__ Xn) {
  const int m = blockIdx.x >> 7, g = blockIdx.x & 127, i0 = g * 2;
  const float* Xm = Xs + (size_t)m * MSZ;
  const uint4* A4 = (const uint4*)(Acp + (size_t)m * (128 * 256));
  float* Xo = Xn + (size_t)m * MSZ;
  const int t = threadIdx.x, h = t >> 6, u = t & 63;
  __shared__ float xs[2][260];
  __shared__ unsigned int buf0[2][132];
  __shared__ unsigned int buf1[2][132];
  __shared__ float red[7][64][9];

  if (t < 128) {
    const int r = t >> 6, c16 = t & 63;
    const float4 v = *(const float4*)&Xm[(i0 + r) * 256 + c16 * 4];
    *(float4*)&xs[r][c16 * 4] = v;
    buf0[r][2 * c16]     = pkh(v.x, v.y);
    buf0[r][2 * c16 + 1] = pkh(v.z, v.w);
  }
  __syncthreads();

  const int kp0 = h * 16;
  float out[2][4];
  if (h == 0) {
#pragma unroll
    for (int i = 0; i < 2; ++i)
#pragma unroll
      for (int j = 0; j < 4; ++j) out[i][j] = D9_0 * xs[i][u * 4 + j];
  }

#pragma unroll
  for (int p = 0; p < 4; ++p) {
    const float cp = (p == 0) ? D9_1 : (p == 1) ? D9_2 : (p == 2) ? D9_3 : D9_4;
    unsigned int (*src)[132] = (p & 1) ? buf1 : buf0;
    unsigned int (*dst)[132] = (p & 1) ? buf0 : buf1;

    float acc[2][4];
#pragma unroll
    for (int i = 0; i < 2; ++i)
#pragma unroll
      for (int j = 0; j < 4; ++j) acc[i][j] = 0.f;
#pragma unroll 8
    for (int kk = 0; kk < 16; ++kk) {
      const int kp = kp0 + kk;
      const uint4 aw = A4[kp * 64 + u];
      const half2_t b0 = uh(aw.x), b1 = uh(aw.y), b2 = uh(aw.z), b3 = uh(aw.w);
#pragma unroll
      for (int r = 0; r < 2; ++r) {
        const half2_t xp = uh(src[r][kp]);
        acc[r][0] = FDOT2(xp, b0, acc[r][0]);
        acc[r][1] = FDOT2(xp, b1, acc[r][1]);
        acc[r][2] = FDOT2(xp, b2, acc[r][2]);
        acc[r][3] = FDOT2(xp, b3, acc[r][3]);
      }
    }
    if (h) {
      float* rr = &red[h - 1][u][0];
#pragma unroll
      for (int i = 0; i < 2; ++i)
#pragma unroll
        for (int j = 0; j < 4; ++j) rr[i * 4 + j] = acc[i][j];
    }
    __syncthreads();
    if (h == 0) {
#pragma unroll
      for (int i = 0; i < 2; ++i) {
        float tv[4];
#pragma unroll
        for (int j = 0; j < 4; ++j) {
          float s = acc[i][j];
#pragma unroll
          for (int q = 0; q < 7; ++q) s += red[q][u][i * 4 + j];
          tv[j] = s;
          out[i][j] += cp * s;
        }
        if (p < 3) {
          dst[i][2 * u]     = pkh(tv[0], tv[1]);
          dst[i][2 * u + 1] = pkh(tv[2], tv[3]);
        }
      }
    }
    __syncthreads();
  }

  if (h == 0) {
#pragma unroll
    for (int i = 0; i < 2; ++i)
      *(float4*)&Xo[(i0 + i) * 256 + u * 4] =
          make_float4(out[i][0], out[i][1], out[i][2], out[i][3]);
  }
}

// ---------------- K4: fused h1-reduce + MLP + selection + output assembly ----------------
// blocks 0..127: per-batch head path; blocks 128..2175: float4 tail copy.
__global__ __launch_bounds__(256) void k_out(const float* __restrict__ sp,
                                             const float* __restrict__ h1p,
                                             const float* __restrict__ b1,
                                             const float* __restrict__ W2,
                                             const float* __restrict__ b2,
                                             const float* __restrict__ W3,
                                             const float* __restrict__ b3,
                                             const float* __restrict__ P,
                                             float* __restrict__ out) {
  const int t = threadIdx.x;
  if (blockIdx.x < 128) {
    const int b = blockIdx.x;
    __shared__ float hd[256];
    __shared__ float h1s[128];
    __shared__ float h2s[64];
    __shared__ int sel_s;
    hd[t] = sp[(size_t)b * Kd + t];
    if (t < 128) {  // h1[b][t] = relu(sum_c h1p[c][b][t] + b1[t]), fp64 sum
      double s = 0.0;
      const float* hp = h1p + b * F1 + t;
#pragma unroll 8
      for (int c = 0; c < NCH; ++c) s += (double)hp[(size_t)c * (Bn * F1)];
      h1s[t] = fmaxf((float)s + b1[t], 0.f);
    }
    __syncthreads();
    if (t < 64) {   // h2 = relu(W2 h1 + b2), fp32
      const float* wr = W2 + t * F1;
      float s = b2[t];
      for (int k = 0; k < F1; ++k) s += h1s[k] * wr[k];
      h2s[t] = fmaxf(s, 0.f);
    }
    __syncthreads();
    if (t == 0) {   // syndrome in fp64, strict-> argmax (first-max ties)
      float best = -1.f;
      int bi = 0;
      bool needed = false;
      for (int j = 0; j < 8; ++j) {
        double s = (double)b3[j];
        const float* wr = W3 + j * F2;
        for (int k = 0; k < F2; ++k) s += (double)h2s[k] * (double)wr[k];
        const float a = fabsf((float)s);
        if (a > 1e-4f) needed = true;
        if (a > best) { best = a; bi = j; }
      }
      sel_s = needed ? (bi % NM) : -1;
    }
    __syncthreads();
    const int s = sel_s;
    if (s < 0) {
      out[(size_t)b * Kd + t] = hd[t];
    } else {
      const float4* prow = (const float4*)(P + (size_t)s * MSZ + t * 256);
      float acc = 0.f;
#pragma unroll 8
      for (int j4 = 0; j4 < 64; ++j4) {
        const float4 p = prow[j4];
        acc += p.x * hd[4 * j4 + 0] + p.y * hd[4 * j4 + 1] +
               p.z * hd[4 * j4 + 2] + p.w * hd[4 * j4 + 3];
      }
      out[(size_t)b * Kd + t] = hd[t] + 0.1f * acc;
    }
  } else {
    const int ci = blockIdx.x - 128;
    const float4* in4 = (const float4*)sp;
    float4* out4 = (float4*)out;
    const int total = Bn * (Kd / 4);
    for (int i = ci * 256 + t; i < total; i += 2048 * 256) {
      const int pos = i & ((Kd / 4) - 1);
      if (pos >= Qd / 4) out4[i] = in4[i];
    }
  }
}

// ---------------- host ----------------
extern "C" void kernel_launch(void* const* d_in, const int* in_sizes, int n_in,
                              void* d_out, int out_size, void* d_ws, size_t ws_size,
                              hipStream_t stream) {
  (void)in_sizes; (void)n_in; (void)out_size; (void)ws_size;
  const float* sp = (const float*)d_in[0];
  const float* W1 = (const float*)d_in[1];
  const float* b1 = (const float*)d_in[2];
  const float* W2 = (const float*)d_in[3];
  const float* b2 = (const float*)d_in[4];
  const float* W3 = (const float*)d_in[5];
  const float* b3 = (const float*)d_in[6];
  const float* ops = (const float*)d_in[7];
  float* out = (float*)d_out;
  float* ws = (float*)d_ws;

  float* h1p  = ws + OFF_H1P;
  float* part = ws + OFF_PART;
  float* Xa   = ws + OFF_XA;
  float* Xb   = ws + OFF_XB;
  unsigned int* Acp = (unsigned int*)(ws + OFF_ACP);

  k_gemm1<<<NCH, 256, 0, stream>>>(sp, W1, h1p);

  // 7 Muon iterations (first folds the 1/s scale), then degree-9 convergent
  k_pA<<<NM * 36, 512, 0, stream>>>(ops, Acp, part);
  k_pB<<<NM * 128, 512, 0, stream>>>(ops, Acp, part, Xa, MA, MB, MC, 1);

  float* X = Xa;
  float* Xn = Xb;
  for (int it = 1; it < 7; ++it) {
    k_pA<<<NM * 36, 512, 0, stream>>>(X, Acp, part);
    k_pB<<<NM * 128, 512, 0, stream>>>(X, Acp, part, Xn, MA, MB, MC, 0);
    float* tmp = X; X = Xn; Xn = tmp;
  }
  k_pA<<<NM * 36, 512, 0, stream>>>(X, Acp, part);
  k_pB9<<<NM * 128, 512, 0, stream>>>(X, Acp, Xn);
  X = Xn;

  k_out<<<128 + 2048, 256, 0, stream>>>(sp, h1p, b1, W2, b2, W3, b3, X, out);
}

// Round 19
// 145.383 us; speedup vs baseline: 1.8292x; 1.1196x over previous
//
#include <hip/hip_runtime.h>
#include <math.h>

// ---------------- problem constants ----------------
constexpr int Bn  = 128;
constexpr int Kd  = 65536;    // magnitude dim (phase half of feats is zeros)
constexpr int F1  = 128;
constexpr int F2  = 64;
constexpr int NM  = 3;
constexpr int Qd  = 256;
constexpr int NCH = 256;      // split-K chunks for big GEMM
constexpr int KC  = 256;      // k per chunk
constexpr int MSZ = 256 * 256;

// Muon (growth) quintic Newton-Schulz coefficients
#define MA 3.4445f
#define MB (-4.7750f)
#define MC 2.0315f
// degree-9 convergent NS: x*(315 - 420y + 378y^2 - 180y^3 + 35y^4)/128, y=x^2
#define D9_0 (315.f / 128.f)
#define D9_1 (-420.f / 128.f)
#define D9_2 (378.f / 128.f)
#define D9_3 (-180.f / 128.f)
#define D9_4 (35.f / 128.f)

// ---------------- ws layout (float offsets) ----------------
constexpr size_t OFF_H1P  = 0;                                   // 256*128*128 floats
constexpr size_t OFF_PART = OFF_H1P + (size_t)NCH * Bn * F1;     // 24 -> pad 64
constexpr size_t OFF_XA   = OFF_PART + 64;
constexpr size_t OFF_XB   = OFF_XA + (size_t)NM * MSZ;
constexpr size_t OFF_ACP  = OFF_XB + (size_t)NM * MSZ;           // u32: NM*128*256

// ---------------- f16 helpers (NS chain) ----------------
typedef __fp16 half2_t __attribute__((ext_vector_type(2)));
union HU { half2_t h; unsigned int u; };
__device__ __forceinline__ unsigned int pkh(float x, float y) {
  HU v; v.h = __builtin_amdgcn_cvt_pkrtz(x, y); return v.u;
}
__device__ __forceinline__ half2_t uh(unsigned int u) { HU v; v.u = u; return v.h; }

#if __has_builtin(__builtin_amdgcn_fdot2)
#define FDOT2(a, b, c) __builtin_amdgcn_fdot2((a), (b), (c), false)
#else
#define FDOT2(a, b, c) ((c) + (float)(a)[0] * (float)(b)[0] + (float)(a)[1] * (float)(b)[1])
#endif

// ---------------- bf16 helpers (MFMA GEMM) ----------------
typedef short bf16x8 __attribute__((ext_vector_type(8)));
typedef float f32x4 __attribute__((ext_vector_type(4)));
__device__ __forceinline__ unsigned short bh(float x) {   // RNE fp32 -> bf16
  unsigned int bx = __float_as_uint(x);
  return (unsigned short)((bx + 0x7FFFu + ((bx >> 16) & 1u)) >> 16);
}
__device__ __forceinline__ float bf(unsigned short h) {
  return __uint_as_float((unsigned int)h << 16);
}

// ---------------- K1: split-K magnitude GEMM via bf16-split MFMA ----------------
// 256 blocks x 256 thr; block = k-chunk of 256 (4 subchunks of 64).
__global__ __launch_bounds__(256) void k_gemm1(const float* __restrict__ sp,
                                               const float* __restrict__ W1,
                                               float* __restrict__ h1p) {
  __shared__ short Ah[128][72];
  __shared__ short Al[128][72];
  __shared__ short Bh[128][72];
  __shared__ short Bl[128][72];
  const int t = threadIdx.x;
  const int w = t >> 6, l = t & 63;
  const int l15 = l & 15, lg = l >> 4;
  const int ch = blockIdx.x;
  const size_t k0 = (size_t)ch * KC;
  const int srow = t >> 4;
  const int skq  = (t & 15) * 4;

  f32x4 acc[2][8];
#pragma unroll
  for (int r = 0; r < 2; ++r)
#pragma unroll
    for (int c = 0; c < 8; ++c) acc[r][c] = (f32x4){0.f, 0.f, 0.f, 0.f};

#pragma unroll
  for (int sub = 0; sub < 4; ++sub) {
    __syncthreads();
    const size_t kb = k0 + sub * 64 + skq;
#pragma unroll
    for (int rep = 0; rep < 8; ++rep) {
      const int row = srow + rep * 16;
      const float4 av = *(const float4*)(sp + (size_t)row * Kd + kb);
      const float4 bv = *(const float4*)(W1 + (size_t)row * (2 * Kd) + kb);
      float va[4] = {fabsf(av.x), fabsf(av.y), fabsf(av.z), fabsf(av.w)};
      float vb[4] = {bv.x, bv.y, bv.z, bv.w};
      unsigned short ha[4], la[4], hb[4], lb[4];
#pragma unroll
      for (int e = 0; e < 4; ++e) {
        ha[e] = bh(va[e]); la[e] = bh(va[e] - bf(ha[e]));
        hb[e] = bh(vb[e]); lb[e] = bh(vb[e] - bf(hb[e]));
      }
      *(uint2*)&Ah[row][skq] = make_uint2((unsigned)ha[0] | ((unsigned)ha[1] << 16),
                                          (unsigned)ha[2] | ((unsigned)ha[3] << 16));
      *(uint2*)&Al[row][skq] = make_uint2((unsigned)la[0] | ((unsigned)la[1] << 16),
                                          (unsigned)la[2] | ((unsigned)la[3] << 16));
      *(uint2*)&Bh[row][skq] = make_uint2((unsigned)hb[0] | ((unsigned)hb[1] << 16),
                                          (unsigned)hb[2] | ((unsigned)hb[3] << 16));
      *(uint2*)&Bl[row][skq] = make_uint2((unsigned)lb[0] | ((unsigned)lb[1] << 16),
                                          (unsigned)lb[2] | ((unsigned)lb[3] << 16));
    }
    __syncthreads();
#pragma unroll
    for (int ks = 0; ks < 2; ++ks) {
      const int ko = ks * 32 + lg * 8;
      bf16x8 afh[2], afl[2];
#pragma unroll
      for (int r = 0; r < 2; ++r) {
        const int row = w * 32 + r * 16 + l15;
        afh[r] = *(const bf16x8*)&Ah[row][ko];
        afl[r] = *(const bf16x8*)&Al[row][ko];
      }
#pragma unroll
      for (int c = 0; c < 8; ++c) {
        const int col = c * 16 + l15;
        const bf16x8 bfh = *(const bf16x8*)&Bh[col][ko];
        const bf16x8 bfl = *(const bf16x8*)&Bl[col][ko];
#pragma unroll
        for (int r = 0; r < 2; ++r) {
          acc[r][c] = __builtin_amdgcn_mfma_f32_16x16x32_bf16(afh[r], bfh, acc[r][c], 0, 0, 0);
          acc[r][c] = __builtin_amdgcn_mfma_f32_16x16x32_bf16(afh[r], bfl, acc[r][c], 0, 0, 0);
          acc[r][c] = __builtin_amdgcn_mfma_f32_16x16x32_bf16(afl[r], bfh, acc[r][c], 0, 0, 0);
        }
      }
    }
  }

  float* outp = h1p + (size_t)ch * (Bn * F1);
#pragma unroll
  for (int r = 0; r < 2; ++r)
#pragma unroll
    for (int c = 0; c < 8; ++c) {
      const int col = c * 16 + l15;
#pragma unroll
      for (int reg = 0; reg < 4; ++reg) {
        const int row = w * 32 + r * 16 + lg * 4 + reg;
        outp[row * F1 + col] = acc[r][c][reg];
      }
    }
}

// ---------------- NS phase A: A = X^T X -> f16 colpk (symmetric 32x32 tiles) ----------------
// [k][c] LDS layout (pitch 36): staging and inner loop use b128 LDS ops.
__global__ __launch_bounds__(512) void k_pA(const float* __restrict__ Xs,
                                            unsigned int* __restrict__ Acp,
                                            float* __restrict__ part) {
  const int bid = blockIdx.x;
  const int m = bid / 36;
  int rem = bid % 36;
  int I = 0;
  while (rem >= 8 - I) { rem -= 8 - I; ++I; }
  const int J = I + rem;
  const float* Xm = Xs + (size_t)m * MSZ;
  unsigned int* Am = Acp + (size_t)m * (128 * 256);
  __shared__ float PI[256][36];
  __shared__ float PJb[256][36];
  __shared__ float red[7][64][20];
  __shared__ float tr8[8];
  float (*PJ)[36] = (I == J) ? PI : PJb;
  const int t = threadIdx.x;

#pragma unroll
  for (int it = 0; it < 4; ++it) {
    const int task = it * 512 + t;
    const int k = task >> 3, c4 = task & 7;
    const float4 vI = *(const float4*)&Xm[k * 256 + I * 32 + c4 * 4];
    *(float4*)&PI[k][c4 * 4] = vI;
    if (I != J) {
      const float4 vJ = *(const float4*)&Xm[k * 256 + J * 32 + c4 * 4];
      *(float4*)&PJb[k][c4 * 4] = vJ;
    }
  }
  __syncthreads();

  const int h = t >> 6, u = t & 63, ur = u >> 3, uc = u & 7;
  float a[4][4];
#pragma unroll
  for (int i = 0; i < 4; ++i)
#pragma unroll
    for (int j = 0; j < 4; ++j) a[i][j] = 0.f;

  const int kb = h * 32;
#pragma unroll 8
  for (int kk = 0; kk < 32; ++kk) {
    const int k = kb + kk;
    const float4 xi4 = *(const float4*)&PI[k][ur * 4];
    const float4 xj4 = *(const float4*)&PJ[k][uc * 4];
    const float xi[4] = {xi4.x, xi4.y, xi4.z, xi4.w};
    const float xj[4] = {xj4.x, xj4.y, xj4.z, xj4.w};
#pragma unroll
    for (int i = 0; i < 4; ++i)
#pragma unroll
      for (int j = 0; j < 4; ++j) a[i][j] += xi[i] * xj[j];
  }
  if (h) {
    float* rr = &red[h - 1][u][0];
#pragma unroll
    for (int i = 0; i < 4; ++i)
      *(float4*)&rr[i * 4] = make_float4(a[i][0], a[i][1], a[i][2], a[i][3]);
  }
  __syncthreads();
  if (h == 0) {
#pragma unroll
    for (int i = 0; i < 4; ++i)
#pragma unroll
      for (int j = 0; j < 4; ++j) {
        float s = a[i][j];
#pragma unroll
        for (int q = 0; q < 7; ++q) s += red[q][u][i * 4 + j];
        a[i][j] = s;
      }
    const int gr = I * 32 + ur * 4, gc = J * 32 + uc * 4;
    {
      const int kp = gr >> 1;
      *(uint4*)&Am[kp * 256 + gc] =
          make_uint4(pkh(a[0][0], a[1][0]), pkh(a[0][1], a[1][1]),
                     pkh(a[0][2], a[1][2]), pkh(a[0][3], a[1][3]));
      *(uint4*)&Am[(kp + 1) * 256 + gc] =
          make_uint4(pkh(a[2][0], a[3][0]), pkh(a[2][1], a[3][1]),
                     pkh(a[2][2], a[3][2]), pkh(a[2][3], a[3][3]));
    }
    if (I != J) {
      const int kp = gc >> 1;
      *(uint4*)&Am[kp * 256 + gr] =
          make_uint4(pkh(a[0][0], a[0][1]), pkh(a[1][0], a[1][1]),
                     pkh(a[2][0], a[2][1]), pkh(a[3][0], a[3][1]));
      *(uint4*)&Am[(kp + 1) * 256 + gr] =
          make_uint4(pkh(a[0][2], a[0][3]), pkh(a[1][2], a[1][3]),
                     pkh(a[2][2], a[2][3]), pkh(a[3][2], a[3][3]));
    } else if (ur == uc) {
      tr8[ur] = a[0][0] + a[1][1] + a[2][2] + a[3][3];
    }
  }
  if (I == J) {
    __syncthreads();
    if (t == 0) {
      float s = 0.f;
#pragma unroll
      for (int q = 0; q < 8; ++q) s += tr8[q];
      part[m * 8 + I] = s;
    }
  }
}

// ---------------- NS phase B (Muon quintic), 2-row strips (grid NM*128) ----------------
__global__ __launch_bounds__(512) void k_pB(const float* __restrict__ Xs,
                                            const unsigned int* __restrict__ Acp,
                                            const float* __restrict__ part,
                                            float* __restrict__ Xn,
                                            const float qa, const float qb, const float qc,
                                            const int first) {
  const int m = blockIdx.x >> 7, g = blockIdx.x & 127, i0 = g * 2;
  const float* Xm = Xs + (size_t)m * MSZ;
  const uint4* A4 = (const uint4*)(Acp + (size_t)m * (128 * 256));
  float* Xo = Xn + (size_t)m * MSZ;
  const int t = threadIdx.x, h = t >> 6, u = t & 63;
  __shared__ float xs[2][260];
  __shared__ unsigned int xsp[2][132];
  __shared__ unsigned int ysp[2][132];
  __shared__ float red[7][64][9];

  float ca = qa, cb = qb, cc = qc;
  if (first) {
    float tr = 0.f;
#pragma unroll
    for (int q = 0; q < 8; ++q) tr += part[m * 8 + q];
    const float s = 0.15f * sqrtf(tr);     // 1.2 * 2*||C||_F/sqrt(256)
    const float is = 1.f / s, is2 = is * is;
    ca = qa * is;
    cb = qb * is * is2;
    cc = qc * is * is2 * is2;
  }

  if (t < 128) {  // stage 2-row X strip: fp32 + f16 pairs
    const int r = t >> 6, c16 = t & 63;
    const float4 v = *(const float4*)&Xm[(i0 + r) * 256 + c16 * 4];
    *(float4*)&xs[r][c16 * 4] = v;
    xsp[r][2 * c16]     = pkh(v.x, v.y);
    xsp[r][2 * c16 + 1] = pkh(v.z, v.w);
  }
  __syncthreads();

  const int kp0 = h * 16;
  float accY[2][4];
#pragma unroll
  for (int i = 0; i < 2; ++i)
#pragma unroll
    for (int j = 0; j < 4; ++j) accY[i][j] = 0.f;
#pragma unroll 8
  for (int kk = 0; kk < 16; ++kk) {
    const int kp = kp0 + kk;
    const uint4 aw = A4[kp * 64 + u];
    const half2_t b0 = uh(aw.x), b1 = uh(aw.y), b2 = uh(aw.z), b3 = uh(aw.w);
#pragma unroll
    for (int r = 0; r < 2; ++r) {
      const half2_t xp = uh(xsp[r][kp]);
      accY[r][0] = FDOT2(xp, b0, accY[r][0]);
      accY[r][1] = FDOT2(xp, b1, accY[r][1]);
      accY[r][2] = FDOT2(xp, b2, accY[r][2]);
      accY[r][3] = FDOT2(xp, b3, accY[r][3]);
    }
  }
  if (h) {
    float* rr = &red[h - 1][u][0];
#pragma unroll
    for (int i = 0; i < 2; ++i)
#pragma unroll
      for (int j = 0; j < 4; ++j) rr[i * 4 + j] = accY[i][j];
  }
  __syncthreads();
  float yv[2][4];
  if (h == 0) {
#pragma unroll
    for (int i = 0; i < 2; ++i)
#pragma unroll
      for (int j = 0; j < 4; ++j) {
        float s = accY[i][j];
#pragma unroll
        for (int q = 0; q < 7; ++q) s += red[q][u][i * 4 + j];
        yv[i][j] = s;
      }
#pragma unroll
    for (int i = 0; i < 2; ++i) {
      ysp[i][2 * u]     = pkh(yv[i][0], yv[i][1]);
      ysp[i][2 * u + 1] = pkh(yv[i][2], yv[i][3]);
    }
  }
  __syncthreads();

  float accZ[2][4];
#pragma unroll
  for (int i = 0; i < 2; ++i)
#pragma unroll
    for (int j = 0; j < 4; ++j) accZ[i][j] = 0.f;
#pragma unroll 8
  for (int kk = 0; kk < 16; ++kk) {
    const int kp = kp0 + kk;
    const uint4 aw = A4[kp * 64 + u];
    const half2_t b0 = uh(aw.x), b1 = uh(aw.y), b2 = uh(aw.z), b3 = uh(aw.w);
#pragma unroll
    for (int r = 0; r < 2; ++r) {
      const half2_t yp = uh(ysp[r][kp]);
      accZ[r][0] = FDOT2(yp, b0, accZ[r][0]);
      accZ[r][1] = FDOT2(yp, b1, accZ[r][1]);
      accZ[r][2] = FDOT2(yp, b2, accZ[r][2]);
      accZ[r][3] = FDOT2(yp, b3, accZ[r][3]);
    }
  }
  if (h) {
    float* rr = &red[h - 1][u][0];
#pragma unroll
    for (int i = 0; i < 2; ++i)
#pragma unroll
      for (int j = 0; j < 4; ++j) rr[i * 4 + j] = accZ[i][j];
  }
  __syncthreads();
  if (h == 0) {
#pragma unroll
    for (int i = 0; i < 2; ++i) {
      float o[4];
#pragma unroll
      for (int j = 0; j < 4; ++j) {
        float z = accZ[i][j];
#pragma unroll
        for (int q = 0; q < 7; ++q) z += red[q][u][i * 4 + j];
        o[j] = ca * xs[i][u * 4 + j] + cb * yv[i][j] + cc * z;
      }
      *(float4*)&Xo[(i0 + i) * 256 + u * 4] = make_float4(o[0], o[1], o[2], o[3]);
    }
  }
}

// ---------------- NS phase B9 (degree-9 convergent), 2-row strips (grid NM*128) ----------------
__global__ __launch_bounds__(512) void k_pB9(const float* __restrict__ Xs,
                                             const unsigned int* __restrict__ Acp,
                                             float* __restrict__ Xn) {
  const int m = blockIdx.x >> 7, g = blockIdx.x & 127, i0 = g * 2;
  const float* Xm = Xs + (size_t)m * MSZ;
  const uint4* A4 = (const uint4*)(Acp + (size_t)m * (128 * 256));
  float* Xo = Xn + (size_t)m * MSZ;
  const int t = threadIdx.x, h = t >> 6, u = t & 63;
  __shared__ float xs[2][260];
  __shared__ unsigned int buf0[2][132];
  __shared__ unsigned int buf1[2][132];
  __shared__ float red[7][64][9];

  if (t < 128) {
    const int r = t >> 6, c16 = t & 63;
    const float4 v = *(const float4*)&Xm[(i0 + r) * 256 + c16 * 4];
    *(float4*)&xs[r][c16 * 4] = v;
    buf0[r][2 * c16]     = pkh(v.x, v.y);
    buf0[r][2 * c16 + 1] = pkh(v.z, v.w);
  }
  __syncthreads();

  const int kp0 = h * 16;
  float out[2][4];
  if (h == 0) {
#pragma unroll
    for (int i = 0; i < 2; ++i)
#pragma unroll
      for (int j = 0; j < 4; ++j) out[i][j] = D9_0 * xs[i][u * 4 + j];
  }

#pragma unroll
  for (int p = 0; p < 4; ++p) {
    const float cp = (p == 0) ? D9_1 : (p == 1) ? D9_2 : (p == 2) ? D9_3 : D9_4;
    unsigned int (*src)[132] = (p & 1) ? buf1 : buf0;
    unsigned int (*dst)[132] = (p & 1) ? buf0 : buf1;

    float acc[2][4];
#pragma unroll
    for (int i = 0; i < 2; ++i)
#pragma unroll
      for (int j = 0; j < 4; ++j) acc[i][j] = 0.f;
#pragma unroll 8
    for (int kk = 0; kk < 16; ++kk) {
      const int kp = kp0 + kk;
      const uint4 aw = A4[kp * 64 + u];
      const half2_t b0 = uh(aw.x), b1 = uh(aw.y), b2 = uh(aw.z), b3 = uh(aw.w);
#pragma unroll
      for (int r = 0; r < 2; ++r) {
        const half2_t xp = uh(src[r][kp]);
        acc[r][0] = FDOT2(xp, b0, acc[r][0]);
        acc[r][1] = FDOT2(xp, b1, acc[r][1]);
        acc[r][2] = FDOT2(xp, b2, acc[r][2]);
        acc[r][3] = FDOT2(xp, b3, acc[r][3]);
      }
    }
    if (h) {
      float* rr = &red[h - 1][u][0];
#pragma unroll
      for (int i = 0; i < 2; ++i)
#pragma unroll
        for (int j = 0; j < 4; ++j) rr[i * 4 + j] = acc[i][j];
    }
    __syncthreads();
    if (h == 0) {
#pragma unroll
      for (int i = 0; i < 2; ++i) {
        float tv[4];
#pragma unroll
        for (int j = 0; j < 4; ++j) {
          float s = acc[i][j];
#pragma unroll
          for (int q = 0; q < 7; ++q) s += red[q][u][i * 4 + j];
          tv[j] = s;
          out[i][j] += cp * s;
        }
        if (p < 3) {
          dst[i][2 * u]     = pkh(tv[0], tv[1]);
          dst[i][2 * u + 1] = pkh(tv[2], tv[3]);
        }
      }
    }
    __syncthreads();
  }

  if (h == 0) {
#pragma unroll
    for (int i = 0; i < 2; ++i)
      *(float4*)&Xo[(i0 + i) * 256 + u * 4] =
          make_float4(out[i][0], out[i][1], out[i][2], out[i][3]);
  }
}

// ---------------- K4: fused h1-reduce + MLP + selection + output assembly ----------------
// blocks 0..127: per-batch head path; blocks 128..2175: float4 tail copy.
__global__ __launch_bounds__(256) void k_out(const float* __restrict__ sp,
                                             const float* __restrict__ h1p,
                                             const float* __restrict__ b1,
                                             const float* __restrict__ W2,
                                             const float* __restrict__ b2,
                                             const float* __restrict__ W3,
                                             const float* __restrict__ b3,
                                             const float* __restrict__ P,
                                             float* __restrict__ out) {
  const int t = threadIdx.x;
  if (blockIdx.x < 128) {
    const int b = blockIdx.x;
    __shared__ float hd[256];
    __shared__ double hred[2][128];
    __shared__ float h1s[128];
    __shared__ float h2s[64];
    __shared__ int sel_s;
    hd[t] = sp[(size_t)b * Kd + t];
    {   // h1 fp64 reduce split 2-way: thread = (feature f = t&127, half hf = t>>7)
      const int f = t & 127, hf = t >> 7;
      double s = 0.0;
      const float* hp = h1p + b * F1 + f;
#pragma unroll 8
      for (int c = hf * 128; c < hf * 128 + 128; ++c)
        s += (double)hp[(size_t)c * (Bn * F1)];
      hred[hf][f] = s;
    }
    __syncthreads();
    if (t < 128)
      h1s[t] = fmaxf((float)(hred[0][t] + hred[1][t]) + b1[t], 0.f);
    __syncthreads();
    if (t < 64) {   // h2 = relu(W2 h1 + b2), fp32
      const float* wr = W2 + t * F1;
      float s = b2[t];
      for (int k = 0; k < F1; ++k) s += h1s[k] * wr[k];
      h2s[t] = fmaxf(s, 0.f);
    }
    __syncthreads();
    if (t == 0) {   // syndrome in fp64, strict-> argmax (first-max ties)
      float best = -1.f;
      int bi = 0;
      bool needed = false;
      for (int j = 0; j < 8; ++j) {
        double s = (double)b3[j];
        const float* wr = W3 + j * F2;
        for (int k = 0; k < F2; ++k) s += (double)h2s[k] * (double)wr[k];
        const float a = fabsf((float)s);
        if (a > 1e-4f) needed = true;
        if (a > best) { best = a; bi = j; }
      }
      sel_s = needed ? (bi % NM) : -1;
    }
    __syncthreads();
    const int s = sel_s;
    if (s < 0) {
      out[(size_t)b * Kd + t] = hd[t];
    } else {
      const float4* prow = (const float4*)(P + (size_t)s * MSZ + t * 256);
      float acc = 0.f;
#pragma unroll 8
      for (int j4 = 0; j4 < 64; ++j4) {
        const float4 p = prow[j4];
        acc += p.x * hd[4 * j4 + 0] + p.y * hd[4 * j4 + 1] +
               p.z * hd[4 * j4 + 2] + p.w * hd[4 * j4 + 3];
      }
      out[(size_t)b * Kd + t] = hd[t] + 0.1f * acc;
    }
  } else {
    const int ci = blockIdx.x - 128;
    const float4* in4 = (const float4*)sp;
    float4* out4 = (float4*)out;
    const int total = Bn * (Kd / 4);
    for (int i = ci * 256 + t; i < total; i += 2048 * 256) {
      const int pos = i & ((Kd / 4) - 1);
      if (pos >= Qd / 4) out4[i] = in4[i];
    }
  }
}

// ---------------- host ----------------
extern "C" void kernel_launch(void* const* d_in, const int* in_sizes, int n_in,
                              void* d_out, int out_size, void* d_ws, size_t ws_size,
                              hipStream_t stream) {
  (void)in_sizes; (void)n_in; (void)out_size; (void)ws_size;
  const float* sp = (const float*)d_in[0];
  const float* W1 = (const float*)d_in[1];
  const float* b1 = (const float*)d_in[2];
  const float* W2 = (const float*)d_in[3];
  const float* b2 = (const float*)d_in[4];
  const float* W3 = (const float*)d_in[5];
  const float* b3 = (const float*)d_in[6];
  const float* ops = (const float*)d_in[7];
  float* out = (float*)d_out;
  float* ws = (float*)d_ws;

  float* h1p  = ws + OFF_H1P;
  float* part = ws + OFF_PART;
  float* Xa   = ws + OFF_XA;
  float* Xb   = ws + OFF_XB;
  unsigned int* Acp = (unsigned int*)(ws + OFF_ACP);

  k_gemm1<<<NCH, 256, 0, stream>>>(sp, W1, h1p);

  // 6 Muon iterations (first folds the 1/s scale), then degree-9 convergent
  k_pA<<<NM * 36, 512, 0, stream>>>(ops, Acp, part);
  k_pB<<<NM * 128, 512, 0, stream>>>(ops, Acp, part, Xa, MA, MB, MC, 1);

  float* X = Xa;
  float* Xn = Xb;
  for (int it = 1; it < 6; ++it) {
    k_pA<<<NM * 36, 512, 0, stream>>>(X, Acp, part);
    k_pB<<<NM * 128, 512, 0, stream>>>(X, Acp, part, Xn, MA, MB, MC, 0);
    float* tmp = X; X = Xn; Xn = tmp;
  }
  k_pA<<<NM * 36, 512, 0, stream>>>(X, Acp, part);
  k_pB9<<<NM * 128, 512, 0, stream>>>(X, Acp, Xn);
  X = Xn;

  k_out<<<128 + 2048, 256, 0, stream>>>(sp, h1p, b1, W2, b2, W3, b3, X, out);
}